// Round 1
// baseline (374.511 us; speedup 1.0000x reference)
//
#include <hip/hip_runtime.h>
#include <math.h>

typedef __attribute__((ext_vector_type(8))) short bf16x8;
typedef __attribute__((ext_vector_type(4))) float f32x4;
typedef __attribute__((ext_vector_type(4))) int   i32x4;

#define NHh 16
#define Sq  2048
#define HIDq 1024
#define HDq 64

__device__ __forceinline__ unsigned short f2bf(float f){
  union { float f; unsigned u; } v; v.f = f;
  unsigned r = v.u + 0x7fffu + ((v.u >> 16) & 1u);   // RNE
  return (unsigned short)(r >> 16);
}
__device__ __forceinline__ float bf2f(unsigned short s){
  union { unsigned u; float f; } v; v.u = ((unsigned)s) << 16;
  return v.f;
}

// ---------------- convert x (f32 -> bf16), 8 elems/thread ----------------
__global__ __launch_bounds__(256) void convert_x(const float* __restrict__ in,
                                                 unsigned short* __restrict__ out, int n8){
  int i = blockIdx.x*256 + threadIdx.x;
  if (i >= n8) return;
  const f32x4* p = (const f32x4*)(in + (size_t)i*8);
  f32x4 a = p[0], b = p[1];
  union { unsigned short us[8]; i32x4 v; } o;
  #pragma unroll
  for (int j=0;j<4;j++){ o.us[j] = f2bf(a[j]); o.us[4+j] = f2bf(b[j]); }
  *(i32x4*)(out + (size_t)i*8) = o.v;
}

// ------------- transpose+convert weights: w[K][N] f32 -> wT[N][K] bf16 -------------
__global__ __launch_bounds__(256) void transpose_w(const float* __restrict__ w0, const float* __restrict__ w1,
                                                   const float* __restrict__ w2, const float* __restrict__ w3,
                                                   unsigned short* __restrict__ wT){
  __shared__ float tile[32][33];
  int z = blockIdx.z;
  const float* w = (z==0)?w0:(z==1)?w1:(z==2)?w2:w3;
  unsigned short* dst = wT + (size_t)z*HIDq*HIDq;
  int tx = threadIdx.x, ty = threadIdx.y;
  int n0 = blockIdx.x*32, k0 = blockIdx.y*32;
  #pragma unroll
  for (int i=ty;i<32;i+=8) tile[i][tx] = w[(size_t)(k0+i)*HIDq + n0+tx];
  __syncthreads();
  #pragma unroll
  for (int i=ty;i<32;i+=8) dst[(size_t)(n0+i)*HIDq + k0+tx] = f2bf(tile[tx][i]);
}

// ------------- GEMM: C[M][N] = A[M][K](bf16) @ Bt[N][K]^T + bias -------------
// EPI 0: f32 row-major out.  EPI 1: bf16 out relayout to (B,NH,S,HD), val half (d<32) scaled.
template<int EPI>
__global__ __launch_bounds__(256) void gemm_bt(const unsigned short* __restrict__ A,
                                               const unsigned short* __restrict__ Bt,
                                               const float* __restrict__ bias,
                                               void* __restrict__ Cout,
                                               int M, int N, int K, float vscale){
  __shared__ unsigned short As[128*40];
  __shared__ unsigned short Bs[128*40];
  const int t = threadIdx.x;
  const int row0 = blockIdx.y*128, col0 = blockIdx.x*128;
  const int wv = t>>6, lane = t&63, g = lane>>4, lr = lane&15;
  const int wr = (wv>>1)*64, wc = (wv&1)*64;
  f32x4 acc[4][4] = {};
  const unsigned short* Ag = A  + (size_t)row0*K;
  const unsigned short* Bg = Bt + (size_t)col0*K;

  for (int k0=0; k0<K; k0+=32){
    __syncthreads();
    #pragma unroll
    for (int i=0;i<2;i++){
      int flat = t + i*256;
      int row = flat>>2, kc = (flat&3)*8;
      *(i32x4*)&As[row*40+kc] = *(const i32x4*)(Ag + (size_t)row*K + k0 + kc);
      *(i32x4*)&Bs[row*40+kc] = *(const i32x4*)(Bg + (size_t)row*K + k0 + kc);
    }
    __syncthreads();
    bf16x8 af[4], bfv[4];
    #pragma unroll
    for (int m=0;m<4;m++) af[m]  = *(bf16x8*)&As[(wr+m*16+lr)*40 + g*8];
    #pragma unroll
    for (int n=0;n<4;n++) bfv[n] = *(bf16x8*)&Bs[(wc+n*16+lr)*40 + g*8];
    #pragma unroll
    for (int m=0;m<4;m++)
      #pragma unroll
      for (int n=0;n<4;n++)
        acc[m][n] = __builtin_amdgcn_mfma_f32_16x16x32_bf16(af[m], bfv[n], acc[m][n], 0,0,0);
  }

  if (EPI == 0){
    float* C = (float*)Cout;
    #pragma unroll
    for (int m=0;m<4;m++){
      int row = row0 + wr + m*16 + g*4;
      #pragma unroll
      for (int n=0;n<4;n++){
        int col = col0 + wc + n*16 + lr;
        float bb = bias[col];
        #pragma unroll
        for (int r=0;r<4;r++) C[(size_t)(row+r)*N + col] = acc[m][n][r] + bb;
      }
    }
  } else {
    unsigned short* E = (unsigned short*)Cout;
    #pragma unroll
    for (int m=0;m<4;m++){
      int rowb = row0 + wr + m*16 + g*4;
      #pragma unroll
      for (int n=0;n<4;n++){
        int col = col0 + wc + n*16 + lr;
        int hh = col >> 6, d = col & 63;
        float bb = bias[col];
        float sc = (d < 32) ? vscale : 1.0f;
        #pragma unroll
        for (int r=0;r<4;r++){
          int row = rowb + r;
          int b_ = row >> 11, ss = row & 2047;
          E[(((size_t)b_*NHh + hh)*Sq + ss)*HDq + d] = f2bf((acc[m][n][r] + bb)*sc);
        }
      }
    }
  }
}

// ------------- flash attention with val/type split scores -------------
// grid (S/64, NH, B), 256 threads (4 waves x 16 q-rows). K-tile = 32 keys.
__global__ __launch_bounds__(256) void attn_kernel(
    const unsigned short* __restrict__ Qe, const unsigned short* __restrict__ Ke,
    const unsigned short* __restrict__ Ve, const float* __restrict__ Tb,
    const float* __restrict__ tbias, const int* __restrict__ mask,
    unsigned short* __restrict__ Obuf)
{
  __shared__ float          qls[64][33];
  __shared__ unsigned short qtls[64][40];
  __shared__ unsigned short Ks[32][72];
  __shared__ unsigned short VT[64][40];
  __shared__ unsigned short Pl[4][16][40];
  __shared__ int msk[32];

  const float NEG_INF = -__builtin_inff();
  const int t  = threadIdx.x;
  const int q0 = blockIdx.x*64;
  const int h  = blockIdx.y;
  const int b  = blockIdx.z;
  const int wv = t>>6, lane = t&63, g = lane>>4, lr = lane&15;

  const size_t headoff = ((size_t)b*NHh + h)*(size_t)Sq*HDq;
  const unsigned short* Qb = Qe + headoff + (size_t)q0*HDq;
  const unsigned short* Kb = Ke + headoff;
  const unsigned short* Vb = Ve + headoff;

  // prologue: stage q_type (f32) then qt = q_type @ T[h] (bf16 in LDS)
  {
    int row = t>>2, c8 = (t&3)*8;
    bf16x8 v = *(const bf16x8*)(Qb + row*HDq + 32 + c8);
    #pragma unroll
    for (int j=0;j<8;j++) qls[row][c8+j] = bf2f((unsigned short)v[j]);
  }
  __syncthreads();
  {
    int row = t&63, e0 = (t>>6)*8;
    const float* Th = Tb + (size_t)h*1024;
    float a[8] = {};
    #pragma unroll 4
    for (int d=0; d<32; d++){
      float qd = qls[row][d];
      const f32x4* tp = (const f32x4*)(Th + d*32 + e0);
      f32x4 t0 = tp[0], t1 = tp[1];
      a[0]+=qd*t0[0]; a[1]+=qd*t0[1]; a[2]+=qd*t0[2]; a[3]+=qd*t0[3];
      a[4]+=qd*t1[0]; a[5]+=qd*t1[1]; a[6]+=qd*t1[2]; a[7]+=qd*t1[3];
    }
    union { unsigned short us[8]; i32x4 v; } pk;
    #pragma unroll
    for (int j=0;j<8;j++) pk.us[j] = f2bf(a[j]);
    *(i32x4*)&qtls[row][e0] = pk.v;
  }
  bf16x8 qvf = *(const bf16x8*)(Qb + (wv*16+lr)*HDq + g*8);   // val half, pre-scaled
  __syncthreads();
  bf16x8 qtf = *(const bf16x8*)&qtls[wv*16+lr][g*8];

  const float tb = tbias[h];
  float mrow[4] = {NEG_INF, NEG_INF, NEG_INF, NEG_INF};
  float lrow[4] = {};
  f32x4 o[4] = {};
  const f32x4 zf = {0.f,0.f,0.f,0.f};

  for (int kt=0; kt<Sq; kt+=32){
    __syncthreads();
    { int row=t>>3, c8=(t&7)*8;
      *(i32x4*)&Ks[row][c8] = *(const i32x4*)(Kb + (size_t)(kt+row)*HDq + c8); }
    { int k=t&31, d0=(t>>5)*8;
      bf16x8 v = *(const bf16x8*)(Vb + (size_t)(kt+k)*HDq + d0);
      #pragma unroll
      for (int j=0;j<8;j++) VT[d0+j][k] = (unsigned short)v[j]; }
    if (t < 32) msk[t] = mask[(size_t)b*Sq + kt + t];
    __syncthreads();

    f32x4 sv[2], st[2];
    #pragma unroll
    for (int ks=0; ks<2; ks++){
      bf16x8 kf0 = *(const bf16x8*)&Ks[ks*16+lr][g*8];
      bf16x8 kf1 = *(const bf16x8*)&Ks[ks*16+lr][32 + g*8];
      sv[ks] = __builtin_amdgcn_mfma_f32_16x16x32_bf16(qvf, kf0, zf, 0,0,0);
      st[ks] = __builtin_amdgcn_mfma_f32_16x16x32_bf16(qtf, kf1, zf, 0,0,0);
    }
    float s[2][4];
    int mk0 = msk[lr], mk1 = msk[16+lr];
    #pragma unroll
    for (int r=0;r<4;r++){
      float t0 = st[0][r] + tb;
      float t1 = st[1][r] + tb;
      float sg0 = 1.f/(1.f + __expf(-t0));
      float sg1 = 1.f/(1.f + __expf(-t1));
      s[0][r] = mk0 ? (sv[0][r] + __logf(sg0 + 1e-6f)) : NEG_INF;
      s[1][r] = mk1 ? (sv[1][r] + __logf(sg1 + 1e-6f)) : NEG_INF;
    }
    float p0a[4], p1a[4], alpha[4];
    #pragma unroll
    for (int r=0;r<4;r++){
      float mx = fmaxf(s[0][r], s[1][r]);
      mx = fmaxf(mx, __shfl_xor(mx,1));
      mx = fmaxf(mx, __shfl_xor(mx,2));
      mx = fmaxf(mx, __shfl_xor(mx,4));
      mx = fmaxf(mx, __shfl_xor(mx,8));
      float mn = fmaxf(mrow[r], mx);
      float al, p0, p1;
      if (mn == NEG_INF){ al = 1.f; p0 = 0.f; p1 = 0.f; }
      else {
        al = __expf(mrow[r] - mn);
        p0 = (s[0][r] == NEG_INF) ? 0.f : __expf(s[0][r] - mn);
        p1 = (s[1][r] == NEG_INF) ? 0.f : __expf(s[1][r] - mn);
      }
      float rs = p0 + p1;
      rs += __shfl_xor(rs,1); rs += __shfl_xor(rs,2);
      rs += __shfl_xor(rs,4); rs += __shfl_xor(rs,8);
      lrow[r] = lrow[r]*al + rs;
      mrow[r] = mn;
      alpha[r] = al; p0a[r] = p0; p1a[r] = p1;
    }
    #pragma unroll
    for (int db=0; db<4; db++){
      o[db][0]*=alpha[0]; o[db][1]*=alpha[1]; o[db][2]*=alpha[2]; o[db][3]*=alpha[3];
    }
    #pragma unroll
    for (int r=0;r<4;r++){
      Pl[wv][g*4+r][lr]      = f2bf(p0a[r]);
      Pl[wv][g*4+r][16 + lr] = f2bf(p1a[r]);
    }
    __syncthreads();
    bf16x8 pf = *(const bf16x8*)&Pl[wv][lr][g*8];
    #pragma unroll
    for (int db=0; db<4; db++){
      bf16x8 vf = *(const bf16x8*)&VT[db*16+lr][g*8];
      o[db] = __builtin_amdgcn_mfma_f32_16x16x32_bf16(pf, vf, o[db], 0,0,0);
    }
  }

  #pragma unroll
  for (int r=0;r<4;r++){
    float inv = (lrow[r] > 0.f) ? 1.f/lrow[r] : 0.f;
    size_t base = ((size_t)b*Sq + (q0 + wv*16 + g*4 + r))*HIDq + (size_t)h*HDq;
    #pragma unroll
    for (int db=0; db<4; db++)
      Obuf[base + db*16 + lr] = f2bf(o[db][r]*inv);
  }
}

extern "C" void kernel_launch(void* const* d_in, const int* in_sizes, int n_in,
                              void* d_out, int out_size, void* d_ws, size_t ws_size,
                              hipStream_t stream) {
  const float* x     = (const float*)d_in[0];
  const float* q_w   = (const float*)d_in[1];
  const float* q_b   = (const float*)d_in[2];
  const float* k_w   = (const float*)d_in[3];
  const float* k_b   = (const float*)d_in[4];
  const float* v_w   = (const float*)d_in[5];
  const float* v_b   = (const float*)d_in[6];
  const float* out_w = (const float*)d_in[7];
  const float* out_b = (const float*)d_in[8];
  const float* Tb    = (const float*)d_in[9];
  const float* tbias = (const float*)d_in[10];
  const int*   mask  = (const int*)d_in[11];

  const size_t MROWS = 4096;             // B*S
  unsigned short* xbf  = (unsigned short*)d_ws;           // 4M
  unsigned short* wT   = xbf  + MROWS*HIDq;               // 4 x 1M (q,k,v,out transposed)
  unsigned short* Qeff = wT   + (size_t)4*HIDq*HIDq;      // 4M  (B,NH,S,HD), val pre-scaled
  unsigned short* Keff = Qeff + MROWS*HIDq;               // 4M
  unsigned short* Veff = Keff + MROWS*HIDq;               // 4M
  unsigned short* Obuf = Veff + MROWS*HIDq;               // 4M  (B,S,HID) bf16
  // total 24M shorts = 48 MB

  convert_x<<<dim3((MROWS*HIDq/8 + 255)/256), dim3(256), 0, stream>>>(x, xbf, (int)(MROWS*HIDq/8));
  transpose_w<<<dim3(32,32,4), dim3(32,8), 0, stream>>>(q_w, k_w, v_w, out_w, wT);

  dim3 gg(HIDq/128, MROWS/128);
  const float vs = 0.17677669529663687f;  // 1/sqrt(32)
  gemm_bt<1><<<gg, 256, 0, stream>>>(xbf, wT + (size_t)0*HIDq*HIDq, q_b, Qeff, (int)MROWS, HIDq, HIDq, vs);
  gemm_bt<1><<<gg, 256, 0, stream>>>(xbf, wT + (size_t)1*HIDq*HIDq, k_b, Keff, (int)MROWS, HIDq, HIDq, 1.0f);
  gemm_bt<1><<<gg, 256, 0, stream>>>(xbf, wT + (size_t)2*HIDq*HIDq, v_b, Veff, (int)MROWS, HIDq, HIDq, 1.0f);

  attn_kernel<<<dim3(Sq/64, NHh, 2), dim3(256), 0, stream>>>(Qeff, Keff, Veff, Tb, tbias, mask, Obuf);

  gemm_bt<0><<<gg, 256, 0, stream>>>(Obuf, wT + (size_t)3*HIDq*HIDq, out_b, d_out, (int)MROWS, HIDq, HIDq, 1.0f);
}

// Round 2
// 207.974 us; speedup vs baseline: 1.8008x; 1.8008x over previous
//
#include <hip/hip_runtime.h>
#include <math.h>

typedef __attribute__((ext_vector_type(8))) short bf16x8;
typedef __attribute__((ext_vector_type(4))) float f32x4;
typedef __attribute__((ext_vector_type(4))) int   i32x4;

#define NHh 16
#define Sq  2048
#define HIDq 1024
#define HDq 64

#if __has_builtin(__builtin_amdgcn_exp2f)
#define EXP2F(x) __builtin_amdgcn_exp2f(x)
#else
#define EXP2F(x) exp2f(x)
#endif
#if __has_builtin(__builtin_amdgcn_rcpf)
#define RCPF(x) __builtin_amdgcn_rcpf(x)
#else
#define RCPF(x) (1.0f/(x))
#endif

__device__ __forceinline__ unsigned short f2bf(float f){
  union { float f; unsigned u; } v; v.f = f;
  unsigned r = v.u + 0x7fffu + ((v.u >> 16) & 1u);   // RNE
  return (unsigned short)(r >> 16);
}
__device__ __forceinline__ float bf2f(unsigned short s){
  union { unsigned u; float f; } v; v.u = ((unsigned)s) << 16;
  return v.f;
}

// ---------------- convert x (f32 -> bf16), 8 elems/thread ----------------
__global__ __launch_bounds__(256) void convert_x(const float* __restrict__ in,
                                                 unsigned short* __restrict__ out, int n8){
  int i = blockIdx.x*256 + threadIdx.x;
  if (i >= n8) return;
  const f32x4* p = (const f32x4*)(in + (size_t)i*8);
  f32x4 a = p[0], b = p[1];
  union { unsigned short us[8]; i32x4 v; } o;
  #pragma unroll
  for (int j=0;j<4;j++){ o.us[j] = f2bf(a[j]); o.us[4+j] = f2bf(b[j]); }
  *(i32x4*)(out + (size_t)i*8) = o.v;
}

// ------------- transpose+convert weights: w[K][N] f32 -> wT[N][K] bf16 -------------
__global__ __launch_bounds__(256) void transpose_w(const float* __restrict__ w0, const float* __restrict__ w1,
                                                   const float* __restrict__ w2, const float* __restrict__ w3,
                                                   unsigned short* __restrict__ wT){
  __shared__ float tile[32][33];
  int z = blockIdx.z;
  const float* w = (z==0)?w0:(z==1)?w1:(z==2)?w2:w3;
  unsigned short* dst = wT + (size_t)z*HIDq*HIDq;
  int tx = threadIdx.x, ty = threadIdx.y;
  int n0 = blockIdx.x*32, k0 = blockIdx.y*32;
  #pragma unroll
  for (int i=ty;i<32;i+=8) tile[i][tx] = w[(size_t)(k0+i)*HIDq + n0+tx];
  __syncthreads();
  #pragma unroll
  for (int i=ty;i<32;i+=8) dst[(size_t)(n0+i)*HIDq + k0+tx] = f2bf(tile[tx][i]);
}

// ------------- shared GEMM main loop: acc += A[128,1024] * Bt[128,1024]^T -------------
__device__ __forceinline__ void gemm_core(const unsigned short* __restrict__ Ag,
                                          const unsigned short* __restrict__ Bg,
                                          unsigned short* As, unsigned short* Bs,
                                          int t, int wr, int wc, int lr, int g,
                                          f32x4 acc[4][4]){
  for (int k0=0; k0<HIDq; k0+=32){
    __syncthreads();
    #pragma unroll
    for (int i=0;i<2;i++){
      int flat = t + i*256;
      int row = flat>>2, kc = (flat&3)*8;
      *(i32x4*)&As[row*40+kc] = *(const i32x4*)(Ag + (size_t)row*HIDq + k0 + kc);
      *(i32x4*)&Bs[row*40+kc] = *(const i32x4*)(Bg + (size_t)row*HIDq + k0 + kc);
    }
    __syncthreads();
    bf16x8 af[4], bfv[4];
    #pragma unroll
    for (int m=0;m<4;m++) af[m]  = *(bf16x8*)&As[(wr+m*16+lr)*40 + g*8];
    #pragma unroll
    for (int n=0;n<4;n++) bfv[n] = *(bf16x8*)&Bs[(wc+n*16+lr)*40 + g*8];
    #pragma unroll
    for (int m=0;m<4;m++)
      #pragma unroll
      for (int n=0;n<4;n++)
        acc[m][n] = __builtin_amdgcn_mfma_f32_16x16x32_bf16(af[m], bfv[n], acc[m][n], 0,0,0);
  }
}

// ------------- fused QKV projection -------------
// grid (24, 32): xb<16 -> Q|K (cols 0..2047), xb>=16 -> V transposed-output GEMM.
__global__ __launch_bounds__(256) void gemm_qkv(const unsigned short* __restrict__ xbf,
    const unsigned short* __restrict__ wT,
    const float* __restrict__ q_b, const float* __restrict__ k_b, const float* __restrict__ v_b,
    unsigned short* __restrict__ Qeff, unsigned short* __restrict__ Keff,
    unsigned short* __restrict__ Vt){
  __shared__ unsigned short As[128*40];
  __shared__ unsigned short Bs[128*40];
  const int t = threadIdx.x;
  const int wv = t>>6, lane = t&63, g = lane>>4, lr = lane&15;
  const int wr = (wv>>1)*64, wc = (wv&1)*64;
  f32x4 acc[4][4] = {};
  const int xb = blockIdx.x, yb = blockIdx.y;
  const float LOG2E = 1.4426950408889634f;
  const float VS = 0.25501335f;   // log2e / sqrt(32)

  if (xb < 16){
    const int row0 = yb*128, col0 = xb*128;
    gemm_core(xbf + (size_t)row0*HIDq, wT + (size_t)col0*HIDq, As, Bs, t, wr, wc, lr, g, acc);
    #pragma unroll
    for (int m=0;m<4;m++){
      int rowb = row0 + wr + m*16 + g*4;
      #pragma unroll
      for (int n=0;n<4;n++){
        int col = col0 + wc + n*16 + lr;
        int seg = col >> 10, cw = col & 1023;
        int hh = cw >> 6, d = cw & 63;
        float bb = seg ? k_b[cw] : q_b[cw];
        float sc = seg ? 1.0f : (d < 32 ? VS : LOG2E);
        unsigned short* E = seg ? Keff : Qeff;
        #pragma unroll
        for (int r=0;r<4;r++){
          int row = rowb + r;
          int b_ = row >> 11, ss = row & 2047;
          E[(((size_t)b_*NHh + hh)*Sq + ss)*HDq + d] = f2bf((acc[m][n][r] + bb)*sc);
        }
      }
    }
  } else {
    const int row0 = (xb-16)*128, col0 = yb*128;
    gemm_core(wT + (size_t)2*HIDq*HIDq + (size_t)row0*HIDq, xbf + (size_t)col0*HIDq,
              As, Bs, t, wr, wc, lr, g, acc);
    #pragma unroll
    for (int m=0;m<4;m++){
      #pragma unroll
      for (int n=0;n<4;n++){
        int col = col0 + wc + n*16 + lr;
        int b_ = col >> 11, ss = col & 2047;
        #pragma unroll
        for (int r=0;r<4;r++){
          int chan = row0 + wr + m*16 + g*4 + r;
          int hh = chan >> 6, d = chan & 63;
          Vt[(((size_t)b_*NHh + hh)*HDq + d)*Sq + ss] = f2bf(acc[m][n][r] + v_b[chan]);
        }
      }
    }
  }
}

// ------------- output projection: C[M][N] f32 = A@Bt^T + bias -------------
__global__ __launch_bounds__(256) void gemm_out(const unsigned short* __restrict__ A,
                                                const unsigned short* __restrict__ Bt,
                                                const float* __restrict__ bias,
                                                float* __restrict__ C){
  __shared__ unsigned short As[128*40];
  __shared__ unsigned short Bs[128*40];
  const int t = threadIdx.x;
  const int wv = t>>6, lane = t&63, g = lane>>4, lr = lane&15;
  const int wr = (wv>>1)*64, wc = (wv&1)*64;
  const int row0 = blockIdx.y*128, col0 = blockIdx.x*128;
  f32x4 acc[4][4] = {};
  gemm_core(A + (size_t)row0*HIDq, Bt + (size_t)col0*HIDq, As, Bs, t, wr, wc, lr, g, acc);
  #pragma unroll
  for (int m=0;m<4;m++){
    int row = row0 + wr + m*16 + g*4;
    #pragma unroll
    for (int n=0;n<4;n++){
      int col = col0 + wc + n*16 + lr;
      float bb = bias[col];
      #pragma unroll
      for (int r=0;r<4;r++) C[(size_t)(row+r)*HIDq + col] = acc[m][n][r] + bb;
    }
  }
}

// ------------- flash attention, exp2-domain, transposed PV -------------
// grid (S/64, NH, B), 256 threads = 4 waves x 16 q-rows, K-tile = 64.
__global__ __launch_bounds__(256) void attn_kernel(
    const unsigned short* __restrict__ Qe, const unsigned short* __restrict__ Ke,
    const unsigned short* __restrict__ Vt, const float* __restrict__ Tb,
    const float* __restrict__ tbias, const int* __restrict__ mask,
    unsigned short* __restrict__ Obuf)
{
  __shared__ unsigned short Ks[64*64];      // XOR-swizzled [k][d]
  __shared__ unsigned short Vs[64*64];      // XOR-swizzled [d][k]
  __shared__ unsigned short Pl[4][16*72];   // per-wave P [q][k], pad 72
  __shared__ unsigned short qtls[64][40];
  __shared__ float mskf[64];
  __shared__ float xchg[4][16];
  float* qls = (float*)&Pl[0][0];           // 64*33 f32 = 8448 B <= 9216 B

  const int t = threadIdx.x;
  const int q0 = blockIdx.x*64;
  const int h = blockIdx.y, b = blockIdx.z;
  const int wv = t>>6, lane = t&63, g = lane>>4, lr = lane&15;

  const unsigned short* Qb  = Qe + (((size_t)b*NHh + h)*Sq + q0)*HDq;
  const unsigned short* Kb  = Ke + ((size_t)b*NHh + h)*(size_t)Sq*HDq;
  const unsigned short* Vtb = Vt + ((size_t)b*NHh + h)*(size_t)HDq*Sq;
  const int* Mb = mask + (size_t)b*Sq;

  // ---- tile-0 staging loads (issued early, overlap prologue) ----
  const int srw = t>>3, scs = t&7;
  const unsigned short* kg0 = Kb  + (size_t)srw*HDq + scs*8;
  const unsigned short* kg1 = kg0 + 32*HDq;
  const unsigned short* vg0 = Vtb + (size_t)srw*Sq + scs*8;
  const unsigned short* vg1 = vg0 + 32*Sq;
  i32x4 kreg0 = *(const i32x4*)kg0, kreg1 = *(const i32x4*)kg1;
  i32x4 vreg0 = *(const i32x4*)vg0, vreg1 = *(const i32x4*)vg1;
  int mv = (t < 64) ? Mb[t] : 0;
  unsigned short* kl0 = &Ks[srw*64 + ((scs*8) ^ ((srw&7)*8))];
  unsigned short* vl0 = &Vs[srw*64 + ((scs*8) ^ ((srw&7)*8))];

  // ---- prologue: qt = q_type @ T[h]  (q_type pre-scaled by log2e) ----
  {
    int row = t>>2, c8 = (t&3)*8;
    bf16x8 v = *(const bf16x8*)(Qb + (size_t)row*HDq + 32 + c8);
    #pragma unroll
    for (int j=0;j<8;j++) qls[row*33 + c8+j] = bf2f((unsigned short)v[j]);
  }
  __syncthreads();
  {
    int row = t&63, e0 = (t>>6)*8;
    const float* Th = Tb + (size_t)h*1024;
    float a[8] = {};
    #pragma unroll 4
    for (int d=0; d<32; d++){
      float qd = qls[row*33 + d];
      const f32x4* tp = (const f32x4*)(Th + d*32 + e0);
      f32x4 t0 = tp[0], t1 = tp[1];
      a[0]+=qd*t0[0]; a[1]+=qd*t0[1]; a[2]+=qd*t0[2]; a[3]+=qd*t0[3];
      a[4]+=qd*t1[0]; a[5]+=qd*t1[1]; a[6]+=qd*t1[2]; a[7]+=qd*t1[3];
    }
    union { unsigned short us[8]; i32x4 v; } pk;
    #pragma unroll
    for (int j=0;j<8;j++) pk.us[j] = f2bf(a[j]);
    *(i32x4*)&qtls[row][e0] = pk.v;
  }
  bf16x8 qvf = *(const bf16x8*)(Qb + (size_t)(wv*16+lr)*HDq + g*8);   // val half (prescaled)
  __syncthreads();
  bf16x8 qtf = *(const bf16x8*)&qtls[wv*16+lr][g*8];

  const float tb2 = tbias[h] * 1.4426950408889634f;
  f32x4 oT[4] = {};
  f32x4 lsum = {0.f,0.f,0.f,0.f};
  float mrow[4] = {-1e4f,-1e4f,-1e4f,-1e4f};
  unsigned short* Pwr = &Pl[wv][0] + (g*4)*72 + lr;        // + r*72 + ks*16
  const unsigned short* Pfr = &Pl[wv][0] + lr*72 + g*8;    // + ks2*32
  bf16x8 onesf;
  #pragma unroll
  for (int j=0;j<8;j++) onesf[j] = (short)0x3F80;          // bf16 1.0
  const f32x4 zf = {0.f,0.f,0.f,0.f};

  for (int kt=0; kt<Sq; kt+=64){
    __syncthreads();
    *(i32x4*)kl0 = kreg0;  *(i32x4*)(kl0 + 32*64) = kreg1;
    *(i32x4*)vl0 = vreg0;  *(i32x4*)(vl0 + 32*64) = vreg1;
    if (t < 64) mskf[t] = mv ? 0.f : -1e30f;
    __syncthreads();
    if (kt + 64 < Sq){
      kg0 += 64*HDq; kg1 += 64*HDq; vg0 += 64; vg1 += 64;
      kreg0 = *(const i32x4*)kg0; kreg1 = *(const i32x4*)kg1;
      vreg0 = *(const i32x4*)vg0; vreg1 = *(const i32x4*)vg1;
      if (t < 64) mv = Mb[kt + 64 + t];
    }

    // ---- QK^T (val + type halves) ----
    f32x4 sv[4], st[4];
    #pragma unroll
    for (int ks=0; ks<4; ks++){
      int krow = ks*16 + lr;
      const unsigned short* kb = &Ks[krow*64];
      unsigned sw = (unsigned)((krow&7)*8);
      bf16x8 kf0 = *(const bf16x8*)(kb + ((unsigned)(g*8) ^ sw));
      bf16x8 kf1 = *(const bf16x8*)(kb + ((unsigned)(32 + g*8) ^ sw));
      sv[ks] = __builtin_amdgcn_mfma_f32_16x16x32_bf16(qvf, kf0, zf, 0,0,0);
      st[ks] = __builtin_amdgcn_mfma_f32_16x16x32_bf16(qtf, kf1, zf, 0,0,0);
    }
    float madd[4];
    #pragma unroll
    for (int ks=0;ks<4;ks++) madd[ks] = mskf[ks*16+lr];
    #pragma unroll
    for (int ks=0;ks<4;ks++){
      #pragma unroll
      for (int r=0;r<4;r++) sv[ks][r] += madd[ks];
    }

    // ---- defer-max: update only when some score exceeds m+8 (log2 units) ----
    bool updl = false;
    #pragma unroll
    for (int r=0;r<4;r++){
      float mr8 = mrow[r] + 8.f;
      updl = updl | (sv[0][r] > mr8) | (sv[1][r] > mr8) | (sv[2][r] > mr8) | (sv[3][r] > mr8);
    }
    if (__any(updl)){
      float alpha[4];
      #pragma unroll
      for (int r=0;r<4;r++){
        float a = fmaxf(fmaxf(sv[0][r],sv[1][r]), fmaxf(sv[2][r],sv[3][r]));
        a = fmaxf(a, __shfl_xor(a,1)); a = fmaxf(a, __shfl_xor(a,2));
        a = fmaxf(a, __shfl_xor(a,4)); a = fmaxf(a, __shfl_xor(a,8));
        float mn = fmaxf(mrow[r], a);
        alpha[r] = EXP2F(mrow[r] - mn);
        mrow[r] = mn;
      }
      if (lr == 0){
        #pragma unroll
        for (int r=0;r<4;r++) xchg[wv][g*4+r] = alpha[r];
      }
      float aq = xchg[wv][lr];
      #pragma unroll
      for (int db=0; db<4; db++){
        #pragma unroll
        for (int j=0;j<4;j++) oT[db][j] *= aq;
      }
      #pragma unroll
      for (int j=0;j<4;j++) lsum[j] *= aq;
    }

    // ---- p = exp2(sv-m) * sigmoid2(t)  ->  P (bf16, LDS) ----
    #pragma unroll
    for (int ks=0; ks<4; ks++){
      #pragma unroll
      for (int r=0;r<4;r++){
        float e  = EXP2F(sv[ks][r] - mrow[r]);
        float tt = st[ks][r] + tb2;
        float sg = RCPF(1.f + EXP2F(-tt));
        float p = e * sg;
        union { float f; unsigned u; } cv; cv.f = p;
        Pwr[r*72 + ks*16] = (unsigned short)((cv.u + 0x8000u) >> 16);
      }
    }

    // ---- PV (transposed): oT[d][q] += V^T * P ; lsum via ones-MFMA ----
    #pragma unroll
    for (int ks2=0; ks2<2; ks2++){
      bf16x8 pf = *(const bf16x8*)(Pfr + ks2*32);
      lsum = __builtin_amdgcn_mfma_f32_16x16x32_bf16(onesf, pf, lsum, 0,0,0);
      #pragma unroll
      for (int db=0; db<4; db++){
        int vrow = db*16 + lr;
        unsigned swv = (unsigned)((vrow&7)*8);
        bf16x8 vf = *(const bf16x8*)(&Vs[vrow*64] + ((unsigned)(ks2*32 + g*8) ^ swv));
        oT[db] = __builtin_amdgcn_mfma_f32_16x16x32_bf16(vf, pf, oT[db], 0,0,0);
      }
    }
  }

  // ---- epilogue: normalize (lane's q = lr), write Obuf[b][s][hid] ----
  float linv = (lsum[0] > 0.f) ? 1.f/lsum[0] : 0.f;
  int srow = q0 + wv*16 + lr;
  unsigned short* Ob = Obuf + ((size_t)b*Sq + srow)*HIDq + h*HDq;
  #pragma unroll
  for (int db=0; db<4; db++){
    union { unsigned short us[4]; unsigned long long v; } pk;
    #pragma unroll
    for (int j=0;j<4;j++) pk.us[j] = f2bf(oT[db][j]*linv);
    *(unsigned long long*)(Ob + db*16 + g*4) = pk.v;
  }
}

extern "C" void kernel_launch(void* const* d_in, const int* in_sizes, int n_in,
                              void* d_out, int out_size, void* d_ws, size_t ws_size,
                              hipStream_t stream) {
  const float* x     = (const float*)d_in[0];
  const float* q_w   = (const float*)d_in[1];
  const float* q_b   = (const float*)d_in[2];
  const float* k_w   = (const float*)d_in[3];
  const float* k_b   = (const float*)d_in[4];
  const float* v_w   = (const float*)d_in[5];
  const float* v_b   = (const float*)d_in[6];
  const float* out_w = (const float*)d_in[7];
  const float* out_b = (const float*)d_in[8];
  const float* Tb    = (const float*)d_in[9];
  const float* tbias = (const float*)d_in[10];
  const int*   mask  = (const int*)d_in[11];

  const size_t MROWS = 4096;             // B*S
  unsigned short* xbf  = (unsigned short*)d_ws;           // 4M shorts
  unsigned short* wT   = xbf  + MROWS*HIDq;               // 4 x 1M
  unsigned short* Qeff = wT   + (size_t)4*HIDq*HIDq;      // (B,NH,S,HD), prescaled
  unsigned short* Keff = Qeff + MROWS*HIDq;
  unsigned short* Vt   = Keff + MROWS*HIDq;               // (B,NH,HD,S) transposed
  unsigned short* Obuf = Vt   + MROWS*HIDq;               // (B,S,HID) bf16

  convert_x<<<dim3((int)(MROWS*HIDq/8/256)), dim3(256), 0, stream>>>(x, xbf, (int)(MROWS*HIDq/8));
  transpose_w<<<dim3(32,32,4), dim3(32,8), 0, stream>>>(q_w, k_w, v_w, out_w, wT);

  gemm_qkv<<<dim3(24,32), dim3(256), 0, stream>>>(xbf, wT, q_b, k_b, v_b, Qeff, Keff, Vt);

  attn_kernel<<<dim3(Sq/64, NHh, 2), dim3(256), 0, stream>>>(Qeff, Keff, Vt, Tb, tbias, mask, Obuf);

  gemm_out<<<dim3(8,32), dim3(256), 0, stream>>>(Obuf, wT + (size_t)3*HIDq*HIDq, out_b, (float*)d_out);
}

// Round 3
// 193.198 us; speedup vs baseline: 1.9385x; 1.0765x over previous
//
#include <hip/hip_runtime.h>
#include <hip/hip_bf16.h>
#include <math.h>

typedef __attribute__((ext_vector_type(8))) short bf16x8;
typedef __attribute__((ext_vector_type(4))) float f32x4;
typedef __attribute__((ext_vector_type(4))) int   i32x4;

#define NHh 16
#define Sq  2048
#define HIDq 1024
#define HDq 64
#define LOG2E 1.4426950408889634f

#if __has_builtin(__builtin_amdgcn_exp2f)
#define EXP2F(x) __builtin_amdgcn_exp2f(x)
#else
#define EXP2F(x) exp2f(x)
#endif
#if __has_builtin(__builtin_amdgcn_rcpf)
#define RCPF(x) __builtin_amdgcn_rcpf(x)
#else
#define RCPF(x) (1.0f/(x))
#endif

__device__ __forceinline__ unsigned short f2bf(float f){
  union { float f; unsigned u; } v; v.f = f;
  unsigned r = v.u + 0x7fffu + ((v.u >> 16) & 1u);   // RNE
  return (unsigned short)(r >> 16);
}
__device__ __forceinline__ float bf2f(unsigned short s){
  union { unsigned u; float f; } v; v.u = ((unsigned)s) << 16;
  return v.f;
}
// packs 2 f32 -> 1 u32 of 2 bf16 (v_cvt_pk_bf16_f32 via HIP API, RNE)
__device__ __forceinline__ unsigned pk2bf(float lo, float hi){
  union { __hip_bfloat162 h; unsigned u; } w;
  w.h = __float22bfloat162_rn(make_float2(lo, hi));
  return w.u;
}

// async global->LDS, 16B per lane; LDS dest must be wave-uniform base + lane*16
__device__ __forceinline__ void gload_lds16(const unsigned short* g, unsigned short* l){
  __builtin_amdgcn_global_load_lds(
      (const __attribute__((address_space(1))) unsigned int*)g,
      (__attribute__((address_space(3))) unsigned int*)l, 16, 0, 0);
}

// ---------------- convert x (f32 -> bf16) ----------------
__global__ __launch_bounds__(256) void convert_x(const float* __restrict__ in,
                                                 unsigned short* __restrict__ out, int n8){
  int i = blockIdx.x*256 + threadIdx.x;
  if (i >= n8) return;
  const f32x4* p = (const f32x4*)(in + (size_t)i*8);
  f32x4 a = p[0], b = p[1];
  union { unsigned short us[8]; i32x4 v; } o;
  #pragma unroll
  for (int j=0;j<4;j++){ o.us[j] = f2bf(a[j]); o.us[4+j] = f2bf(b[j]); }
  *(i32x4*)(out + (size_t)i*8) = o.v;
}

// ------------- transpose+convert weights: w[K][N] f32 -> wT[N][K] bf16 -------------
__global__ __launch_bounds__(256) void transpose_w(const float* __restrict__ w0, const float* __restrict__ w1,
                                                   const float* __restrict__ w2, const float* __restrict__ w3,
                                                   unsigned short* __restrict__ wT){
  __shared__ float tile[32][33];
  int z = blockIdx.z;
  const float* w = (z==0)?w0:(z==1)?w1:(z==2)?w2:w3;
  unsigned short* dst = wT + (size_t)z*HIDq*HIDq;
  int tx = threadIdx.x, ty = threadIdx.y;
  int n0 = blockIdx.x*32, k0 = blockIdx.y*32;
  #pragma unroll
  for (int i=ty;i<32;i+=8) tile[i][tx] = w[(size_t)(k0+i)*HIDq + n0+tx];
  __syncthreads();
  #pragma unroll
  for (int i=ty;i<32;i+=8) dst[(size_t)(n0+i)*HIDq + k0+tx] = f2bf(tile[tx][i]);
}

// ------------- GEMM main loop (m97 structure): global_load_lds, BK=64, linear LDS -------------
// acc[n][m] holds C[row = wr+m*16+lr][cols = wc+n*16+g*4 .. +3]  (4 consecutive cols/reg)
__device__ __forceinline__ void gemm_core_gl(const unsigned short* __restrict__ Ag,
                                             const unsigned short* __restrict__ Bg,
                                             unsigned short* As, unsigned short* Bs,
                                             int t, int wv, int lane, int wr, int wc, int lr, int g,
                                             f32x4 acc[4][4]){
  for (int k0=0; k0<HIDq; k0+=64){
    __syncthreads();
    #pragma unroll
    for (int j=0;j<4;j++){
      int flat = (j*4+wv)*64 + lane;      // 0..1023
      int row = flat>>3, c8 = (flat&7)*8;
      gload_lds16(Ag + (size_t)row*HIDq + k0 + c8, &As[flat*8]);
      gload_lds16(Bg + (size_t)row*HIDq + k0 + c8, &Bs[flat*8]);
    }
    __syncthreads();
    #pragma unroll
    for (int ks=0; ks<2; ks++){
      bf16x8 af[4], bfv[4];
      #pragma unroll
      for (int m=0;m<4;m++) af[m]  = *(bf16x8*)&As[(wr+m*16+lr)*64 + ks*32 + g*8];
      #pragma unroll
      for (int n=0;n<4;n++) bfv[n] = *(bf16x8*)&Bs[(wc+n*16+lr)*64 + ks*32 + g*8];
      #pragma unroll
      for (int n=0;n<4;n++)
        #pragma unroll
        for (int m=0;m<4;m++)
          acc[n][m] = __builtin_amdgcn_mfma_f32_16x16x32_bf16(bfv[n], af[m], acc[n][m], 0,0,0);
    }
  }
}

// ------------- fused QKV projection -------------
// grid 768 blocks: xb<16 -> Q|K (cols 0..2047), xb>=16 -> V transposed-output GEMM.
__global__ __launch_bounds__(256) void gemm_qkv(const unsigned short* __restrict__ xbf,
    const unsigned short* __restrict__ wT,
    const float* __restrict__ q_b, const float* __restrict__ k_b, const float* __restrict__ v_b,
    unsigned short* __restrict__ Qeff, unsigned short* __restrict__ Keff,
    unsigned short* __restrict__ Vt){
  __shared__ unsigned short As[128*64];
  __shared__ unsigned short Bs[128*64];
  const int t = threadIdx.x;
  const int wv = t>>6, lane = t&63, g = lane>>4, lr = lane&15;
  const int wr = (wv>>1)*64, wc = (wv&1)*64;
  f32x4 acc[4][4] = {};
  // XCD-aware swizzle (768 % 8 == 0)
  int id = blockIdx.y*gridDim.x + blockIdx.x;
  int cpx = (gridDim.x*gridDim.y) >> 3;
  int sid = (id&7)*cpx + (id>>3);
  const int xb = sid % gridDim.x, yb = sid / gridDim.x;
  const float VS = 0.25501335f;   // log2e / sqrt(32)

  if (xb < 16){
    const int row0 = yb*128, col0 = xb*128;
    gemm_core_gl(xbf + (size_t)row0*HIDq, wT + (size_t)col0*HIDq, As, Bs, t, wv, lane, wr, wc, lr, g, acc);
    #pragma unroll
    for (int n=0;n<4;n++){
      #pragma unroll
      for (int m=0;m<4;m++){
        int row = row0 + wr + m*16 + lr;
        int b_ = row>>11, ss = row&2047;
        int colb = col0 + wc + n*16 + g*4;
        int seg = colb>>10, cw = colb&1023;
        int hh = cw>>6, d = cw&63;
        const float* bp = seg ? k_b : q_b;
        f32x4 bb = *(const f32x4*)&bp[cw];
        float sc = seg ? 1.0f : (d < 32 ? VS : -LOG2E);
        unsigned short* E = seg ? Keff : Qeff;
        float v0 = (acc[n][m][0]+bb[0])*sc, v1 = (acc[n][m][1]+bb[1])*sc;
        float v2 = (acc[n][m][2]+bb[2])*sc, v3 = (acc[n][m][3]+bb[3])*sc;
        union { unsigned u[2]; unsigned long long ll; } W;
        W.u[0] = pk2bf(v0,v1); W.u[1] = pk2bf(v2,v3);
        *(unsigned long long*)&E[(((size_t)b_*NHh+hh)*Sq+ss)*HDq + d] = W.ll;
      }
    }
  } else {
    const int row0 = (xb-16)*128, col0 = yb*128;
    gemm_core_gl(wT + (size_t)2*HIDq*HIDq + (size_t)row0*HIDq, xbf + (size_t)col0*HIDq,
                 As, Bs, t, wv, lane, wr, wc, lr, g, acc);
    #pragma unroll
    for (int n=0;n<4;n++){
      #pragma unroll
      for (int m=0;m<4;m++){
        int chan = row0 + wr + m*16 + lr;
        int hh = chan>>6, d = chan&63;
        float bv = v_b[chan];
        int colb = col0 + wc + n*16 + g*4;
        int b_ = colb>>11, ss = colb&2047;
        union { unsigned u[2]; unsigned long long ll; } W;
        W.u[0] = pk2bf(acc[n][m][0]+bv, acc[n][m][1]+bv);
        W.u[1] = pk2bf(acc[n][m][2]+bv, acc[n][m][3]+bv);
        *(unsigned long long*)&Vt[(((size_t)b_*NHh+hh)*HDq + d)*Sq + ss] = W.ll;
      }
    }
  }
}

// ------------- output projection: C f32 = A@Bt^T + bias -------------
__global__ __launch_bounds__(256) void gemm_out(const unsigned short* __restrict__ A,
                                                const unsigned short* __restrict__ Bt,
                                                const float* __restrict__ bias,
                                                float* __restrict__ C){
  __shared__ unsigned short As[128*64];
  __shared__ unsigned short Bs[128*64];
  const int t = threadIdx.x;
  const int wv = t>>6, lane = t&63, g = lane>>4, lr = lane&15;
  const int wr = (wv>>1)*64, wc = (wv&1)*64;
  int id = blockIdx.y*gridDim.x + blockIdx.x;
  int cpx = (gridDim.x*gridDim.y) >> 3;
  int sid = (id&7)*cpx + (id>>3);
  const int xb = sid % gridDim.x, yb = sid / gridDim.x;
  const int row0 = yb*128, col0 = xb*128;
  f32x4 acc[4][4] = {};
  gemm_core_gl(A + (size_t)row0*HIDq, Bt + (size_t)col0*HIDq, As, Bs, t, wv, lane, wr, wc, lr, g, acc);
  #pragma unroll
  for (int n=0;n<4;n++){
    #pragma unroll
    for (int m=0;m<4;m++){
      int row = row0 + wr + m*16 + lr;
      int colb = col0 + wc + n*16 + g*4;
      f32x4 bb = *(const f32x4*)&bias[colb];
      f32x4 o = acc[n][m] + bb;
      *(f32x4*)&C[(size_t)row*HIDq + colb] = o;
    }
  }
}

// ------------- flash attention: swapped QK^T, lane-local softmax, KVBLK=128 -------------
// grid (S/64, NH, B), 256 threads = 4 waves x 16 q rows (q = lr within wave).
__global__ __launch_bounds__(256,3) void attn_kernel(
    const unsigned short* __restrict__ Qe, const unsigned short* __restrict__ Ke,
    const unsigned short* __restrict__ Vt, const float* __restrict__ Tb,
    const float* __restrict__ tbias, const int* __restrict__ mask,
    unsigned short* __restrict__ Obuf)
{
  __shared__ unsigned short Ks[128*64];    // [k][d], granule-XOR swizzled
  __shared__ unsigned short Vs[64*128];    // [d][k], granule-XOR swizzled
  __shared__ unsigned short Pl[4*16*64];   // per-wave P [q=lr][k], swizzled
  __shared__ unsigned short qtls[64*40];
  __shared__ float mskf[128];              // 0 or -1e30 (C-init for sv MFMA)

  const int t = threadIdx.x;
  const int q0 = blockIdx.x*64;
  const int h = blockIdx.y, b = blockIdx.z;
  const int wv = t>>6, lane = t&63, g = lane>>4, lr = lane&15;

  const unsigned short* Qb  = Qe + (((size_t)b*NHh+h)*Sq + q0)*HDq;
  const unsigned short* Kb  = Ke + ((size_t)b*NHh+h)*(size_t)Sq*HDq;
  const unsigned short* Vtb = Vt + ((size_t)b*NHh+h)*(size_t)HDq*Sq;
  const int* Mb = mask + (size_t)b*Sq;

  // ---- prefetch tile 0 into regs (T14) ----
  i32x4 kreg[4], vreg[4];
  #pragma unroll
  for (int i=0;i<4;i++){
    int c = t + i*256;
    int kr = c>>3, kc = (c&7)*8;
    kreg[i] = *(const i32x4*)(Kb + (size_t)kr*HDq + kc);
    int vd = c>>4, vc = (c&15)*8;
    vreg[i] = *(const i32x4*)(Vtb + (size_t)vd*Sq + vc);
  }
  int mv = (t<128) ? Mb[t] : 0;

  // ---- prologue: qt = q_type(-log2e-scaled) @ T[h], to bf16 LDS ----
  float* qls = (float*)Ks;                 // overlay scratch (consumed before loop)
  {
    int row = t>>2, c8 = (t&3)*8;
    bf16x8 v = *(const bf16x8*)(Qb + (size_t)row*HDq + 32 + c8);
    #pragma unroll
    for (int j=0;j<8;j++) qls[row*33 + c8 + j] = bf2f((unsigned short)v[j]);
  }
  __syncthreads();
  {
    int row = t&63, e0 = (t>>6)*8;
    const float* Th = Tb + (size_t)h*1024;
    float a[8] = {};
    #pragma unroll 4
    for (int d=0; d<32; d++){
      float qd = qls[row*33 + d];
      const f32x4* tp = (const f32x4*)(Th + d*32 + e0);
      f32x4 t0 = tp[0], t1 = tp[1];
      a[0]+=qd*t0[0]; a[1]+=qd*t0[1]; a[2]+=qd*t0[2]; a[3]+=qd*t0[3];
      a[4]+=qd*t1[0]; a[5]+=qd*t1[1]; a[6]+=qd*t1[2]; a[7]+=qd*t1[3];
    }
    union { unsigned u[2]; unsigned long long ll; } W0, W1;
    W0.u[0]=pk2bf(a[0],a[1]); W0.u[1]=pk2bf(a[2],a[3]);
    W1.u[0]=pk2bf(a[4],a[5]); W1.u[1]=pk2bf(a[6],a[7]);
    *(unsigned long long*)&qtls[row*40 + e0]     = W0.ll;
    *(unsigned long long*)&qtls[row*40 + e0 + 4] = W1.ll;
  }
  bf16x8 qvf = *(const bf16x8*)(Qb + (size_t)(wv*16+lr)*HDq + g*8);   // val half (prescaled)
  __syncthreads();
  bf16x8 qtn = *(const bf16x8*)&qtls[(wv*16+lr)*40 + g*8];            // type half (neg-scaled)

  const float tbn = -tbias[h]*LOG2E;
  const f32x4 tbc = {tbn,tbn,tbn,tbn};
  f32x4 oT[4] = {};
  f32x4 lsum = {0.f,0.f,0.f,0.f};
  float mrow = -1e4f;                       // per-lane running max (log2 domain), q = lr
  unsigned short* Pw = &Pl[wv*1024 + lr*64];
  const int swp = (lr&7)*8;
  bf16x8 onesf;
  #pragma unroll
  for (int j=0;j<8;j++) onesf[j] = (short)0x3F80;

  for (int kt=0; kt<Sq; kt+=128){
    __syncthreads();
    #pragma unroll
    for (int i=0;i<4;i++){
      int c = t + i*256;
      int kr = c>>3, kc = (c&7)*8;
      *(i32x4*)&Ks[kr*64 + (kc ^ ((kr&7)*8))] = kreg[i];
      int vd = c>>4, vc = (c&15)*8;
      *(i32x4*)&Vs[vd*128 + (vc ^ ((vd&15)*8))] = vreg[i];
    }
    if (t<128) mskf[t] = mv ? 0.f : -1e30f;
    __syncthreads();
    if (kt + 128 < Sq){
      #pragma unroll
      for (int i=0;i<4;i++){
        int c = t + i*256;
        int kr = c>>3, kc = (c&7)*8;
        kreg[i] = *(const i32x4*)(Kb + (size_t)(kt+128+kr)*HDq + kc);
        int vd = c>>4, vc = (c&15)*8;
        vreg[i] = *(const i32x4*)(Vtb + (size_t)vd*Sq + kt + 128 + vc);
      }
      if (t<128) mv = Mb[kt+128+t];
    }

    #pragma unroll
    for (int kh=0; kh<2; kh++){
      // ---- QK^T swapped: lane holds S[q=lr][k = kh*64+16ks+4g+r]; mask/bias in C-init ----
      f32x4 sv[4], st[4];
      #pragma unroll
      for (int ks=0; ks<4; ks++){
        int krow = kh*64 + ks*16 + lr;
        const unsigned short* kb = &Ks[krow*64];
        int sw = (krow&7)*8;
        bf16x8 kf0 = *(const bf16x8*)(kb + ((g*8) ^ sw));
        bf16x8 kf1 = *(const bf16x8*)(kb + ((32 + g*8) ^ sw));
        f32x4 madd = *(const f32x4*)&mskf[kh*64 + ks*16 + g*4];
        sv[ks] = __builtin_amdgcn_mfma_f32_16x16x32_bf16(kf0, qvf, madd, 0,0,0);
        st[ks] = __builtin_amdgcn_mfma_f32_16x16x32_bf16(kf1, qtn, tbc, 0,0,0);
      }
      // ---- lane-local defer-max ----
      float a0 = fmaxf(fmaxf(sv[0][0],sv[0][1]), fmaxf(sv[0][2],sv[0][3]));
      float a1 = fmaxf(fmaxf(sv[1][0],sv[1][1]), fmaxf(sv[1][2],sv[1][3]));
      float a2 = fmaxf(fmaxf(sv[2][0],sv[2][1]), fmaxf(sv[2][2],sv[2][3]));
      float a3 = fmaxf(fmaxf(sv[3][0],sv[3][1]), fmaxf(sv[3][2],sv[3][3]));
      float a = fmaxf(fmaxf(a0,a1), fmaxf(a2,a3));
      a = fmaxf(a, __shfl_xor(a,16));
      a = fmaxf(a, __shfl_xor(a,32));
      if (__any(a > mrow + 8.f)){
        float mn = fmaxf(mrow, a);
        float al = EXP2F(mrow - mn);
        mrow = mn;
        #pragma unroll
        for (int db=0; db<4; db++){
          oT[db][0]*=al; oT[db][1]*=al; oT[db][2]*=al; oT[db][3]*=al;
        }
        lsum[0]*=al; lsum[1]*=al; lsum[2]*=al; lsum[3]*=al;
      }
      // ---- p = exp2(sv-m) * sigmoid; pack pairs; vector LDS write ----
      #pragma unroll
      for (int ks=0; ks<4; ks++){
        float p0 = EXP2F(sv[ks][0]-mrow) * RCPF(1.f + EXP2F(st[ks][0]));
        float p1 = EXP2F(sv[ks][1]-mrow) * RCPF(1.f + EXP2F(st[ks][1]));
        float p2 = EXP2F(sv[ks][2]-mrow) * RCPF(1.f + EXP2F(st[ks][2]));
        float p3 = EXP2F(sv[ks][3]-mrow) * RCPF(1.f + EXP2F(st[ks][3]));
        union { unsigned u[2]; unsigned long long ll; } W;
        W.u[0] = pk2bf(p0,p1); W.u[1] = pk2bf(p2,p3);
        *(unsigned long long*)(Pw + ((ks*16 + g*4) ^ swp)) = W.ll;
      }
      // ---- PV: oT[d][q] += V^T * P ; lsum via ones-MFMA ----
      #pragma unroll
      for (int ks2=0; ks2<2; ks2++){
        bf16x8 pf = *(const bf16x8*)(Pw + ((ks2*32 + g*8) ^ swp));
        lsum = __builtin_amdgcn_mfma_f32_16x16x32_bf16(onesf, pf, lsum, 0,0,0);
        #pragma unroll
        for (int db=0; db<4; db++){
          int vrow = db*16 + lr;
          bf16x8 vf = *(const bf16x8*)(&Vs[vrow*128] + ((kh*64 + ks2*32 + g*8) ^ ((vrow&15)*8)));
          oT[db] = __builtin_amdgcn_mfma_f32_16x16x32_bf16(vf, pf, oT[db], 0,0,0);
        }
      }
    }
  }

  // ---- epilogue: lane q = lr; oT[db][r] = O[d=db*16+4g+r][q] ----
  float linv = (lsum[0] > 0.f) ? RCPF(lsum[0]) : 0.f;
  int srow = q0 + wv*16 + lr;
  unsigned short* Ob = Obuf + ((size_t)b*Sq + srow)*HIDq + h*HDq;
  #pragma unroll
  for (int db=0; db<4; db++){
    union { unsigned u[2]; unsigned long long ll; } W;
    W.u[0] = pk2bf(oT[db][0]*linv, oT[db][1]*linv);
    W.u[1] = pk2bf(oT[db][2]*linv, oT[db][3]*linv);
    *(unsigned long long*)(Ob + db*16 + g*4) = W.ll;
  }
}

extern "C" void kernel_launch(void* const* d_in, const int* in_sizes, int n_in,
                              void* d_out, int out_size, void* d_ws, size_t ws_size,
                              hipStream_t stream) {
  const float* x     = (const float*)d_in[0];
  const float* q_w   = (const float*)d_in[1];
  const float* q_b   = (const float*)d_in[2];
  const float* k_w   = (const float*)d_in[3];
  const float* k_b   = (const float*)d_in[4];
  const float* v_w   = (const float*)d_in[5];
  const float* v_b   = (const float*)d_in[6];
  const float* out_w = (const float*)d_in[7];
  const float* out_b = (const float*)d_in[8];
  const float* Tb    = (const float*)d_in[9];
  const float* tbias = (const float*)d_in[10];
  const int*   mask  = (const int*)d_in[11];

  const size_t MROWS = 4096;             // B*S
  unsigned short* xbf  = (unsigned short*)d_ws;           // 4M shorts
  unsigned short* wT   = xbf  + MROWS*HIDq;               // 4 x 1M
  unsigned short* Qeff = wT   + (size_t)4*HIDq*HIDq;      // (B,NH,S,HD), prescaled
  unsigned short* Keff = Qeff + MROWS*HIDq;
  unsigned short* Vt   = Keff + MROWS*HIDq;               // (B,NH,HD,S) transposed
  unsigned short* Obuf = Vt   + MROWS*HIDq;               // (B,S,HID) bf16

  convert_x<<<dim3((int)(MROWS*HIDq/8/256)), dim3(256), 0, stream>>>(x, xbf, (int)(MROWS*HIDq/8));
  transpose_w<<<dim3(32,32,4), dim3(32,8), 0, stream>>>(q_w, k_w, v_w, out_w, wT);

  gemm_qkv<<<dim3(24,32), dim3(256), 0, stream>>>(xbf, wT, q_b, k_b, v_b, Qeff, Keff, Vt);

  attn_kernel<<<dim3(Sq/64, NHh, 2), dim3(256), 0, stream>>>(Qeff, Keff, Vt, Tb, tbias, mask, Obuf);

  gemm_out<<<dim3(8,32), dim3(256), 0, stream>>>(Obuf, wT + (size_t)3*HIDq*HIDq, out_b, (float*)d_out);
}

// Round 5
// 178.010 us; speedup vs baseline: 2.1039x; 1.0853x over previous
//
#include <hip/hip_runtime.h>
#include <hip/hip_bf16.h>
#include <math.h>

typedef __attribute__((ext_vector_type(8))) short bf16x8;
typedef __attribute__((ext_vector_type(4))) float f32x4;
typedef __attribute__((ext_vector_type(4))) int   i32x4;

#define NHh 16
#define Sq  2048
#define HIDq 1024
#define HDq 64
#define LOG2E 1.4426950408889634f

#if __has_builtin(__builtin_amdgcn_exp2f)
#define EXP2F(x) __builtin_amdgcn_exp2f(x)
#else
#define EXP2F(x) exp2f(x)
#endif
#if __has_builtin(__builtin_amdgcn_rcpf)
#define RCPF(x) __builtin_amdgcn_rcpf(x)
#else
#define RCPF(x) (1.0f/(x))
#endif

__device__ __forceinline__ unsigned short f2bf(float f){
  union { float f; unsigned u; } v; v.f = f;
  unsigned r = v.u + 0x7fffu + ((v.u >> 16) & 1u);   // RNE
  return (unsigned short)(r >> 16);
}
__device__ __forceinline__ float bf2f(unsigned short s){
  union { unsigned u; float f; } v; v.u = ((unsigned)s) << 16;
  return v.f;
}
__device__ __forceinline__ unsigned pk2bf(float lo, float hi){
  union { __hip_bfloat162 h; unsigned u; } w;
  w.h = __float22bfloat162_rn(make_float2(lo, hi));
  return w.u;
}

// async global->LDS, 16B per lane; LDS dest must be wave-uniform base + lane*16
__device__ __forceinline__ void gload_lds16(const unsigned short* g, unsigned short* l){
  __builtin_amdgcn_global_load_lds(
      (const __attribute__((address_space(1))) unsigned int*)g,
      (__attribute__((address_space(3))) unsigned int*)l, 16, 0, 0);
}

// ---------------- convert x (f32 -> bf16) ----------------
__global__ __launch_bounds__(256) void convert_x(const float* __restrict__ in,
                                                 unsigned short* __restrict__ out, int n8){
  int i = blockIdx.x*256 + threadIdx.x;
  if (i >= n8) return;
  const f32x4* p = (const f32x4*)(in + (size_t)i*8);
  f32x4 a = p[0], b = p[1];
  union { unsigned short us[8]; i32x4 v; } o;
  #pragma unroll
  for (int j=0;j<4;j++){ o.us[j] = f2bf(a[j]); o.us[4+j] = f2bf(b[j]); }
  *(i32x4*)(out + (size_t)i*8) = o.v;
}

// ------------- transpose+convert weights: w[K][N] f32 -> wT[N][K] bf16 -------------
__global__ __launch_bounds__(256) void transpose_w(const float* __restrict__ w0, const float* __restrict__ w1,
                                                   const float* __restrict__ w2, const float* __restrict__ w3,
                                                   unsigned short* __restrict__ wT){
  __shared__ float tile[32][33];
  int z = blockIdx.z;
  const float* w = (z==0)?w0:(z==1)?w1:(z==2)?w2:w3;
  unsigned short* dst = wT + (size_t)z*HIDq*HIDq;
  int tx = threadIdx.x, ty = threadIdx.y;
  int n0 = blockIdx.x*32, k0 = blockIdx.y*32;
  #pragma unroll
  for (int i=ty;i<32;i+=8) tile[i][tx] = w[(size_t)(k0+i)*HIDq + n0+tx];
  __syncthreads();
  #pragma unroll
  for (int i=ty;i<32;i+=8) dst[(size_t)(n0+i)*HIDq + k0+tx] = f2bf(tile[tx][i]);
}

// ------------- GEMM main loop (m97 structure): global_load_lds, BK=64, linear LDS -------------
__device__ __forceinline__ void gemm_core_gl(const unsigned short* __restrict__ Ag,
                                             const unsigned short* __restrict__ Bg,
                                             unsigned short* As, unsigned short* Bs,
                                             int t, int wv, int lane, int wr, int wc, int lr, int g,
                                             f32x4 acc[4][4]){
  for (int k0=0; k0<HIDq; k0+=64){
    __syncthreads();
    #pragma unroll
    for (int j=0;j<4;j++){
      int flat = (j*4+wv)*64 + lane;      // 0..1023
      int row = flat>>3, c8 = (flat&7)*8;
      gload_lds16(Ag + (size_t)row*HIDq + k0 + c8, &As[flat*8]);
      gload_lds16(Bg + (size_t)row*HIDq + k0 + c8, &Bs[flat*8]);
    }
    __syncthreads();
    #pragma unroll
    for (int ks=0; ks<2; ks++){
      bf16x8 af[4], bfv[4];
      #pragma unroll
      for (int m=0;m<4;m++) af[m]  = *(bf16x8*)&As[(wr+m*16+lr)*64 + ks*32 + g*8];
      #pragma unroll
      for (int n=0;n<4;n++) bfv[n] = *(bf16x8*)&Bs[(wc+n*16+lr)*64 + ks*32 + g*8];
      #pragma unroll
      for (int n=0;n<4;n++)
        #pragma unroll
        for (int m=0;m<4;m++)
          acc[n][m] = __builtin_amdgcn_mfma_f32_16x16x32_bf16(bfv[n], af[m], acc[n][m], 0,0,0);
    }
  }
}

// ------------- fused QKV projection -------------
__global__ __launch_bounds__(256) void gemm_qkv(const unsigned short* __restrict__ xbf,
    const unsigned short* __restrict__ wT,
    const float* __restrict__ q_b, const float* __restrict__ k_b, const float* __restrict__ v_b,
    unsigned short* __restrict__ Qeff, unsigned short* __restrict__ Keff,
    unsigned short* __restrict__ Vt){
  __shared__ unsigned short As[128*64];
  __shared__ unsigned short Bs[128*64];
  const int t = threadIdx.x;
  const int wv = t>>6, lane = t&63, g = lane>>4, lr = lane&15;
  const int wr = (wv>>1)*64, wc = (wv&1)*64;
  f32x4 acc[4][4] = {};
  int id = blockIdx.y*gridDim.x + blockIdx.x;
  int cpx = (gridDim.x*gridDim.y) >> 3;
  int sid = (id&7)*cpx + (id>>3);
  const int xb = sid % gridDim.x, yb = sid / gridDim.x;
  const float VS = 0.25501335f;   // log2e / sqrt(32)

  if (xb < 16){
    const int row0 = yb*128, col0 = xb*128;
    gemm_core_gl(xbf + (size_t)row0*HIDq, wT + (size_t)col0*HIDq, As, Bs, t, wv, lane, wr, wc, lr, g, acc);
    #pragma unroll
    for (int n=0;n<4;n++){
      #pragma unroll
      for (int m=0;m<4;m++){
        int row = row0 + wr + m*16 + lr;
        int b_ = row>>11, ss = row&2047;
        int colb = col0 + wc + n*16 + g*4;
        int seg = colb>>10, cw = colb&1023;
        int hh = cw>>6, d = cw&63;
        const float* bp = seg ? k_b : q_b;
        f32x4 bb = *(const f32x4*)&bp[cw];
        float sc = seg ? 1.0f : (d < 32 ? VS : -LOG2E);
        unsigned short* E = seg ? Keff : Qeff;
        float v0 = (acc[n][m][0]+bb[0])*sc, v1 = (acc[n][m][1]+bb[1])*sc;
        float v2 = (acc[n][m][2]+bb[2])*sc, v3 = (acc[n][m][3]+bb[3])*sc;
        union { unsigned u[2]; unsigned long long ll; } W;
        W.u[0] = pk2bf(v0,v1); W.u[1] = pk2bf(v2,v3);
        *(unsigned long long*)&E[(((size_t)b_*NHh+hh)*Sq+ss)*HDq + d] = W.ll;
      }
    }
  } else {
    const int row0 = (xb-16)*128, col0 = yb*128;
    gemm_core_gl(wT + (size_t)2*HIDq*HIDq + (size_t)row0*HIDq, xbf + (size_t)col0*HIDq,
                 As, Bs, t, wv, lane, wr, wc, lr, g, acc);
    #pragma unroll
    for (int n=0;n<4;n++){
      #pragma unroll
      for (int m=0;m<4;m++){
        int chan = row0 + wr + m*16 + lr;
        int hh = chan>>6, d = chan&63;
        float bv = v_b[chan];
        int colb = col0 + wc + n*16 + g*4;
        int b_ = colb>>11, ss = colb&2047;   // ss restored (R4 bug: used colb)
        union { unsigned u[2]; unsigned long long ll; } W;
        W.u[0] = pk2bf(acc[n][m][0]+bv, acc[n][m][1]+bv);
        W.u[1] = pk2bf(acc[n][m][2]+bv, acc[n][m][3]+bv);
        *(unsigned long long*)&Vt[(((size_t)b_*NHh+hh)*HDq + d)*Sq + ss] = W.ll;
      }
    }
  }
}

// ------------- output projection: C f32 = A@Bt^T + bias -------------
__global__ __launch_bounds__(256) void gemm_out(const unsigned short* __restrict__ A,
                                                const unsigned short* __restrict__ Bt,
                                                const float* __restrict__ bias,
                                                float* __restrict__ C){
  __shared__ unsigned short As[128*64];
  __shared__ unsigned short Bs[128*64];
  const int t = threadIdx.x;
  const int wv = t>>6, lane = t&63, g = lane>>4, lr = lane&15;
  const int wr = (wv>>1)*64, wc = (wv&1)*64;
  int id = blockIdx.y*gridDim.x + blockIdx.x;
  int cpx = (gridDim.x*gridDim.y) >> 3;
  int sid = (id&7)*cpx + (id>>3);
  const int xb = sid % gridDim.x, yb = sid / gridDim.x;
  const int row0 = yb*128, col0 = xb*128;
  f32x4 acc[4][4] = {};
  gemm_core_gl(A + (size_t)row0*HIDq, Bt + (size_t)col0*HIDq, As, Bs, t, wv, lane, wr, wc, lr, g, acc);
  #pragma unroll
  for (int n=0;n<4;n++){
    #pragma unroll
    for (int m=0;m<4;m++){
      int row = row0 + wr + m*16 + lr;
      int colb = col0 + wc + n*16 + g*4;
      f32x4 bb = *(const f32x4*)&bias[colb];
      f32x4 o = acc[n][m] + bb;
      *(f32x4*)&C[(size_t)row*HIDq + colb] = o;
    }
  }
}

// ------------- flash attention: 8 waves, q-tile 128, KVBLK 128, XCD head-colocation -------------
__global__ __launch_bounds__(512,2) void attn_kernel(
    const unsigned short* __restrict__ Qe, const unsigned short* __restrict__ Ke,
    const unsigned short* __restrict__ Vt, const float* __restrict__ Tb,
    const float* __restrict__ tbias, const int* __restrict__ mask,
    unsigned short* __restrict__ Obuf)
{
  __shared__ __align__(16) unsigned char smem[49664];
  unsigned short* Ks = (unsigned short*)smem;             // [128 k][64 d] swizzled, 16 KB
  unsigned short* Vs = (unsigned short*)(smem + 16384);   // [64 d][128 k] swizzled, 16 KB
  unsigned short* Pl = (unsigned short*)(smem + 32768);   // 8 waves x [16 q][64 k], 16 KB
  float* mskf = (float*)(smem + 49152);                   // 128 f32
  float* qls = (float*)smem;                              // prologue overlay (16.9 KB, consumed pre-loop)
  unsigned short* qtls = Pl;                              // prologue overlay (10.2 KB <= 16 KB)

  const int t = threadIdx.x;
  // XCD-aware decode: all 16 q-blocks of a (b,h) land on one XCD
  const int dd = blockIdx.x;
  const int slot = dd>>3, xcd = dd&7;
  const int x = slot & 15;
  const int bh = ((slot>>4)<<3) | xcd;
  const int h = bh & 15, b = bh >> 4;
  const int q0 = x*128;
  const int wv = t>>6, lane = t&63, g = lane>>4, lr = lane&15;

  const unsigned short* Qb  = Qe + (((size_t)b*NHh+h)*Sq + q0)*HDq;
  const unsigned short* Kb  = Ke + ((size_t)b*NHh+h)*(size_t)Sq*HDq;
  const unsigned short* Vtb = Vt + ((size_t)b*NHh+h)*(size_t)HDq*Sq;
  const int* Mb = mask + (size_t)b*Sq;

  // ---- prefetch tile 0 into regs (T14) ----
  i32x4 kreg[2], vreg[2];
  #pragma unroll
  for (int i=0;i<2;i++){
    int c = t + i*512;
    int kr = c>>3, kc = (c&7)*8;
    kreg[i] = *(const i32x4*)(Kb + (size_t)kr*HDq + kc);
    int vd = c>>4, vc = (c&15)*8;
    vreg[i] = *(const i32x4*)(Vtb + (size_t)vd*Sq + vc);
  }
  int mv = (t<128) ? Mb[t] : 0;

  // ---- prologue: qt = q_type(-log2e-scaled) @ T[h] ----
  {
    int row = t>>2, c8 = (t&3)*8;
    bf16x8 v = *(const bf16x8*)(Qb + (size_t)row*HDq + 32 + c8);
    #pragma unroll
    for (int j=0;j<8;j++) qls[row*33 + c8 + j] = bf2f((unsigned short)v[j]);
  }
  __syncthreads();
  {
    int row = t&127, e0 = (t>>7)*8;
    const float* Th = Tb + (size_t)h*1024;
    float a[8] = {};
    #pragma unroll 4
    for (int d=0; d<32; d++){
      float qd = qls[row*33 + d];
      const f32x4* tp = (const f32x4*)(Th + d*32 + e0);
      f32x4 t0 = tp[0], t1 = tp[1];
      a[0]+=qd*t0[0]; a[1]+=qd*t0[1]; a[2]+=qd*t0[2]; a[3]+=qd*t0[3];
      a[4]+=qd*t1[0]; a[5]+=qd*t1[1]; a[6]+=qd*t1[2]; a[7]+=qd*t1[3];
    }
    union { unsigned u[2]; unsigned long long ll; } W0, W1;
    W0.u[0]=pk2bf(a[0],a[1]); W0.u[1]=pk2bf(a[2],a[3]);
    W1.u[0]=pk2bf(a[4],a[5]); W1.u[1]=pk2bf(a[6],a[7]);
    *(unsigned long long*)&qtls[row*40 + e0]     = W0.ll;
    *(unsigned long long*)&qtls[row*40 + e0 + 4] = W1.ll;
  }
  bf16x8 qvf = *(const bf16x8*)(Qb + (size_t)(wv*16+lr)*HDq + g*8);   // val half (prescaled)
  __syncthreads();
  bf16x8 qtn = *(const bf16x8*)&qtls[(wv*16+lr)*40 + g*8];            // type half (neg-scaled)

  const float tbn = -tbias[h]*LOG2E;
  const f32x4 tbc = {tbn,tbn,tbn,tbn};
  f32x4 oT[4] = {};
  f32x4 lsum = {0.f,0.f,0.f,0.f};
  float mrow = -1e4f;                       // per-lane running max (log2 domain), q = lr
  unsigned short* Pw = &Pl[wv*1024 + lr*64];
  const int swp = (lr&7)*8;
  bf16x8 onesf;
  #pragma unroll
  for (int j=0;j<8;j++) onesf[j] = (short)0x3F80;

  for (int kt=0; kt<Sq; kt+=128){
    __syncthreads();
    #pragma unroll
    for (int i=0;i<2;i++){
      int c = t + i*512;
      int kr = c>>3, kc = (c&7)*8;
      *(i32x4*)&Ks[kr*64 + (kc ^ ((kr&7)*8))] = kreg[i];
      int vd = c>>4, vc = (c&15)*8;
      *(i32x4*)&Vs[vd*128 + (vc ^ ((vd&15)*8))] = vreg[i];
    }
    if (t<128) mskf[t] = mv ? 0.f : -1e30f;
    __syncthreads();
    if (kt + 128 < Sq){
      #pragma unroll
      for (int i=0;i<2;i++){
        int c = t + i*512;
        int kr = c>>3, kc = (c&7)*8;
        kreg[i] = *(const i32x4*)(Kb + (size_t)(kt+128+kr)*HDq + kc);
        int vd = c>>4, vc = (c&15)*8;
        vreg[i] = *(const i32x4*)(Vtb + (size_t)vd*Sq + kt + 128 + vc);
      }
      if (t<128) mv = Mb[kt+128+t];
    }

    #pragma unroll
    for (int kh=0; kh<2; kh++){
      // ---- QK^T swapped: lane holds S[q=lr][k = kh*64+16ks+4g+r] ----
      f32x4 sv[4], st[4];
      __builtin_amdgcn_s_setprio(1);
      #pragma unroll
      for (int ks=0; ks<4; ks++){
        int krow = kh*64 + ks*16 + lr;
        const unsigned short* kb = &Ks[krow*64];
        int sw = (krow&7)*8;
        bf16x8 kf0 = *(const bf16x8*)(kb + ((g*8) ^ sw));
        bf16x8 kf1 = *(const bf16x8*)(kb + ((32 + g*8) ^ sw));
        f32x4 madd = *(const f32x4*)&mskf[kh*64 + ks*16 + g*4];
        sv[ks] = __builtin_amdgcn_mfma_f32_16x16x32_bf16(kf0, qvf, madd, 0,0,0);
        st[ks] = __builtin_amdgcn_mfma_f32_16x16x32_bf16(kf1, qtn, tbc, 0,0,0);
      }
      __builtin_amdgcn_s_setprio(0);
      // ---- lane-local defer-max ----
      float a0 = fmaxf(fmaxf(sv[0][0],sv[0][1]), fmaxf(sv[0][2],sv[0][3]));
      float a1 = fmaxf(fmaxf(sv[1][0],sv[1][1]), fmaxf(sv[1][2],sv[1][3]));
      float a2 = fmaxf(fmaxf(sv[2][0],sv[2][1]), fmaxf(sv[2][2],sv[2][3]));
      float a3 = fmaxf(fmaxf(sv[3][0],sv[3][1]), fmaxf(sv[3][2],sv[3][3]));
      float a = fmaxf(fmaxf(a0,a1), fmaxf(a2,a3));
      a = fmaxf(a, __shfl_xor(a,16));
      a = fmaxf(a, __shfl_xor(a,32));
      if (__any(a > mrow + 8.f)){
        float mn = fmaxf(mrow, a);
        float al = EXP2F(mrow - mn);
        mrow = mn;
        #pragma unroll
        for (int db=0; db<4; db++){
          oT[db][0]*=al; oT[db][1]*=al; oT[db][2]*=al; oT[db][3]*=al;
        }
        lsum[0]*=al; lsum[1]*=al; lsum[2]*=al; lsum[3]*=al;
      }
      // ---- p = exp2(sv-m) * sigmoid; pack pairs; vector LDS write ----
      #pragma unroll
      for (int ks=0; ks<4; ks++){
        float p0 = EXP2F(sv[ks][0]-mrow) * RCPF(1.f + EXP2F(st[ks][0]));
        float p1 = EXP2F(sv[ks][1]-mrow) * RCPF(1.f + EXP2F(st[ks][1]));
        float p2 = EXP2F(sv[ks][2]-mrow) * RCPF(1.f + EXP2F(st[ks][2]));
        float p3 = EXP2F(sv[ks][3]-mrow) * RCPF(1.f + EXP2F(st[ks][3]));
        union { unsigned u[2]; unsigned long long ll; } W;
        W.u[0] = pk2bf(p0,p1); W.u[1] = pk2bf(p2,p3);
        *(unsigned long long*)(Pw + ((ks*16 + g*4) ^ swp)) = W.ll;
      }
      // ---- PV: oT[d][q] += V^T * P ; lsum via ones-MFMA ----
      #pragma unroll
      for (int ks2=0; ks2<2; ks2++){
        bf16x8 pf = *(const bf16x8*)(Pw + ((ks2*32 + g*8) ^ swp));
        __builtin_amdgcn_s_setprio(1);
        lsum = __builtin_amdgcn_mfma_f32_16x16x32_bf16(onesf, pf, lsum, 0,0,0);
        #pragma unroll
        for (int db=0; db<4; db++){
          int vrow = db*16 + lr;
          bf16x8 vf = *(const bf16x8*)(&Vs[vrow*128] + ((kh*64 + ks2*32 + g*8) ^ ((vrow&15)*8)));
          oT[db] = __builtin_amdgcn_mfma_f32_16x16x32_bf16(vf, pf, oT[db], 0,0,0);
        }
        __builtin_amdgcn_s_setprio(0);
      }
    }
  }

  // ---- epilogue: lane q = lr; oT[db][r] = O[d=db*16+4g+r][q] ----
  float linv = (lsum[0] > 0.f) ? RCPF(lsum[0]) : 0.f;
  int srow = q0 + wv*16 + lr;
  unsigned short* Ob = Obuf + ((size_t)b*Sq + srow)*HIDq + h*HDq;
  #pragma unroll
  for (int db=0; db<4; db++){
    union { unsigned u[2]; unsigned long long ll; } W;
    W.u[0] = pk2bf(oT[db][0]*linv, oT[db][1]*linv);
    W.u[1] = pk2bf(oT[db][2]*linv, oT[db][3]*linv);
    *(unsigned long long*)(Ob + db*16 + g*4) = W.ll;
  }
}

extern "C" void kernel_launch(void* const* d_in, const int* in_sizes, int n_in,
                              void* d_out, int out_size, void* d_ws, size_t ws_size,
                              hipStream_t stream) {
  const float* x     = (const float*)d_in[0];
  const float* q_w   = (const float*)d_in[1];
  const float* q_b   = (const float*)d_in[2];
  const float* k_w   = (const float*)d_in[3];
  const float* k_b   = (const float*)d_in[4];
  const float* v_w   = (const float*)d_in[5];
  const float* v_b   = (const float*)d_in[6];
  const float* out_w = (const float*)d_in[7];
  const float* out_b = (const float*)d_in[8];
  const float* Tb    = (const float*)d_in[9];
  const float* tbias = (const float*)d_in[10];
  const int*   mask  = (const int*)d_in[11];

  const size_t MROWS = 4096;             // B*S
  unsigned short* xbf  = (unsigned short*)d_ws;           // 4M shorts
  unsigned short* wT   = xbf  + MROWS*HIDq;               // 4 x 1M
  unsigned short* Qeff = wT   + (size_t)4*HIDq*HIDq;      // (B,NH,S,HD), prescaled
  unsigned short* Keff = Qeff + MROWS*HIDq;
  unsigned short* Vt   = Keff + MROWS*HIDq;               // (B,NH,HD,S) transposed
  unsigned short* Obuf = Vt   + MROWS*HIDq;               // (B,S,HID) bf16

  convert_x<<<dim3((int)(MROWS*HIDq/8/256)), dim3(256), 0, stream>>>(x, xbf, (int)(MROWS*HIDq/8));
  transpose_w<<<dim3(32,32,4), dim3(32,8), 0, stream>>>(q_w, k_w, v_w, out_w, wT);

  gemm_qkv<<<dim3(24,32), dim3(256), 0, stream>>>(xbf, wT, q_b, k_b, v_b, Qeff, Keff, Vt);

  attn_kernel<<<dim3(512), dim3(512), 0, stream>>>(Qeff, Keff, Vt, Tb, tbias, mask, Obuf);

  gemm_out<<<dim3(8,32), dim3(256), 0, stream>>>(Obuf, wT + (size_t)3*HIDq*HIDq, out_b, (float*)d_out);
}

// Round 6
// 173.712 us; speedup vs baseline: 2.1559x; 1.0247x over previous
//
#include <hip/hip_runtime.h>
#include <hip/hip_bf16.h>
#include <math.h>

typedef __attribute__((ext_vector_type(8))) short bf16x8;
typedef __attribute__((ext_vector_type(4))) float f32x4;
typedef __attribute__((ext_vector_type(4))) int   i32x4;

#define NHh 16
#define Sq  2048
#define HIDq 1024
#define HDq 64
#define LOG2E 1.4426950408889634f

#if __has_builtin(__builtin_amdgcn_exp2f)
#define EXP2F(x) __builtin_amdgcn_exp2f(x)
#else
#define EXP2F(x) exp2f(x)
#endif
#if __has_builtin(__builtin_amdgcn_rcpf)
#define RCPF(x) __builtin_amdgcn_rcpf(x)
#else
#define RCPF(x) (1.0f/(x))
#endif

__device__ __forceinline__ unsigned short f2bf(float f){
  union { float f; unsigned u; } v; v.f = f;
  unsigned r = v.u + 0x7fffu + ((v.u >> 16) & 1u);   // RNE
  return (unsigned short)(r >> 16);
}
__device__ __forceinline__ float bf2f(unsigned short s){
  union { unsigned u; float f; } v; v.u = ((unsigned)s) << 16;
  return v.f;
}
__device__ __forceinline__ unsigned pk2bf(float lo, float hi){
  union { __hip_bfloat162 h; unsigned u; } w;
  w.h = __float22bfloat162_rn(make_float2(lo, hi));
  return w.u;
}

// async global->LDS, 16B per lane; LDS dest must be wave-uniform base + lane*16
__device__ __forceinline__ void gload_lds16(const unsigned short* g, unsigned short* l){
  __builtin_amdgcn_global_load_lds(
      (const __attribute__((address_space(1))) unsigned int*)g,
      (__attribute__((address_space(3))) unsigned int*)l, 16, 0, 0);
}

// ---------------- convert x (f32 -> bf16) ----------------
__global__ __launch_bounds__(256) void convert_x(const float* __restrict__ in,
                                                 unsigned short* __restrict__ out, int n8){
  int i = blockIdx.x*256 + threadIdx.x;
  if (i >= n8) return;
  const f32x4* p = (const f32x4*)(in + (size_t)i*8);
  f32x4 a = p[0], b = p[1];
  union { unsigned short us[8]; i32x4 v; } o;
  #pragma unroll
  for (int j=0;j<4;j++){ o.us[j] = f2bf(a[j]); o.us[4+j] = f2bf(b[j]); }
  *(i32x4*)(out + (size_t)i*8) = o.v;
}

// ------------- transpose+convert weights: w[K][N] f32 -> wT[N][K] bf16 -------------
__global__ __launch_bounds__(256) void transpose_w(const float* __restrict__ w0, const float* __restrict__ w1,
                                                   const float* __restrict__ w2, const float* __restrict__ w3,
                                                   unsigned short* __restrict__ wT){
  __shared__ float tile[32][33];
  int z = blockIdx.z;
  const float* w = (z==0)?w0:(z==1)?w1:(z==2)?w2:w3;
  unsigned short* dst = wT + (size_t)z*HIDq*HIDq;
  int tx = threadIdx.x, ty = threadIdx.y;
  int n0 = blockIdx.x*32, k0 = blockIdx.y*32;
  #pragma unroll
  for (int i=ty;i<32;i+=8) tile[i][tx] = w[(size_t)(k0+i)*HIDq + n0+tx];
  __syncthreads();
  #pragma unroll
  for (int i=ty;i<32;i+=8) dst[(size_t)(n0+i)*HIDq + k0+tx] = f2bf(tile[tx][i]);
}

// ------------- GEMM main loop (m97 structure): global_load_lds, BK=64, linear LDS -------------
__device__ __forceinline__ void gemm_core_gl(const unsigned short* __restrict__ Ag,
                                             const unsigned short* __restrict__ Bg,
                                             unsigned short* As, unsigned short* Bs,
                                             int t, int wv, int lane, int wr, int wc, int lr, int g,
                                             f32x4 acc[4][4]){
  for (int k0=0; k0<HIDq; k0+=64){
    __syncthreads();
    #pragma unroll
    for (int j=0;j<4;j++){
      int flat = (j*4+wv)*64 + lane;      // 0..1023
      int row = flat>>3, c8 = (flat&7)*8;
      gload_lds16(Ag + (size_t)row*HIDq + k0 + c8, &As[flat*8]);
      gload_lds16(Bg + (size_t)row*HIDq + k0 + c8, &Bs[flat*8]);
    }
    __syncthreads();
    #pragma unroll
    for (int ks=0; ks<2; ks++){
      bf16x8 af[4], bfv[4];
      #pragma unroll
      for (int m=0;m<4;m++) af[m]  = *(bf16x8*)&As[(wr+m*16+lr)*64 + ks*32 + g*8];
      #pragma unroll
      for (int n=0;n<4;n++) bfv[n] = *(bf16x8*)&Bs[(wc+n*16+lr)*64 + ks*32 + g*8];
      #pragma unroll
      for (int n=0;n<4;n++)
        #pragma unroll
        for (int m=0;m<4;m++)
          acc[n][m] = __builtin_amdgcn_mfma_f32_16x16x32_bf16(bfv[n], af[m], acc[n][m], 0,0,0);
    }
  }
}

// ------------- fused QKV projection -------------
__global__ __launch_bounds__(256) void gemm_qkv(const unsigned short* __restrict__ xbf,
    const unsigned short* __restrict__ wT,
    const float* __restrict__ q_b, const float* __restrict__ k_b, const float* __restrict__ v_b,
    unsigned short* __restrict__ Qeff, unsigned short* __restrict__ Keff,
    unsigned short* __restrict__ Vt){
  __shared__ unsigned short As[128*64];
  __shared__ unsigned short Bs[128*64];
  const int t = threadIdx.x;
  const int wv = t>>6, lane = t&63, g = lane>>4, lr = lane&15;
  const int wr = (wv>>1)*64, wc = (wv&1)*64;
  f32x4 acc[4][4] = {};
  int id = blockIdx.y*gridDim.x + blockIdx.x;
  int cpx = (gridDim.x*gridDim.y) >> 3;
  int sid = (id&7)*cpx + (id>>3);
  const int xb = sid % gridDim.x, yb = sid / gridDim.x;
  const float VS = 0.25501335f;   // log2e / sqrt(32)

  if (xb < 16){
    const int row0 = yb*128, col0 = xb*128;
    gemm_core_gl(xbf + (size_t)row0*HIDq, wT + (size_t)col0*HIDq, As, Bs, t, wv, lane, wr, wc, lr, g, acc);
    #pragma unroll
    for (int n=0;n<4;n++){
      #pragma unroll
      for (int m=0;m<4;m++){
        int row = row0 + wr + m*16 + lr;
        int b_ = row>>11, ss = row&2047;
        int colb = col0 + wc + n*16 + g*4;
        int seg = colb>>10, cw = colb&1023;
        int hh = cw>>6, d = cw&63;
        const float* bp = seg ? k_b : q_b;
        f32x4 bb = *(const f32x4*)&bp[cw];
        float sc = seg ? 1.0f : (d < 32 ? VS : -LOG2E);
        unsigned short* E = seg ? Keff : Qeff;
        float v0 = (acc[n][m][0]+bb[0])*sc, v1 = (acc[n][m][1]+bb[1])*sc;
        float v2 = (acc[n][m][2]+bb[2])*sc, v3 = (acc[n][m][3]+bb[3])*sc;
        union { unsigned u[2]; unsigned long long ll; } W;
        W.u[0] = pk2bf(v0,v1); W.u[1] = pk2bf(v2,v3);
        *(unsigned long long*)&E[(((size_t)b_*NHh+hh)*Sq+ss)*HDq + d] = W.ll;
      }
    }
  } else {
    const int row0 = (xb-16)*128, col0 = yb*128;
    gemm_core_gl(wT + (size_t)2*HIDq*HIDq + (size_t)row0*HIDq, xbf + (size_t)col0*HIDq,
                 As, Bs, t, wv, lane, wr, wc, lr, g, acc);
    #pragma unroll
    for (int n=0;n<4;n++){
      #pragma unroll
      for (int m=0;m<4;m++){
        int chan = row0 + wr + m*16 + lr;
        int hh = chan>>6, d = chan&63;
        float bv = v_b[chan];
        int colb = col0 + wc + n*16 + g*4;
        int b_ = colb>>11, ss = colb&2047;
        union { unsigned u[2]; unsigned long long ll; } W;
        W.u[0] = pk2bf(acc[n][m][0]+bv, acc[n][m][1]+bv);
        W.u[1] = pk2bf(acc[n][m][2]+bv, acc[n][m][3]+bv);
        *(unsigned long long*)&Vt[(((size_t)b_*NHh+hh)*HDq + d)*Sq + ss] = W.ll;
      }
    }
  }
}

// ------------- output projection: C f32 = A@Bt^T + bias -------------
__global__ __launch_bounds__(256) void gemm_out(const unsigned short* __restrict__ A,
                                                const unsigned short* __restrict__ Bt,
                                                const float* __restrict__ bias,
                                                float* __restrict__ C){
  __shared__ unsigned short As[128*64];
  __shared__ unsigned short Bs[128*64];
  const int t = threadIdx.x;
  const int wv = t>>6, lane = t&63, g = lane>>4, lr = lane&15;
  const int wr = (wv>>1)*64, wc = (wv&1)*64;
  int id = blockIdx.y*gridDim.x + blockIdx.x;
  int cpx = (gridDim.x*gridDim.y) >> 3;
  int sid = (id&7)*cpx + (id>>3);
  const int xb = sid % gridDim.x, yb = sid / gridDim.x;
  const int row0 = yb*128, col0 = xb*128;
  f32x4 acc[4][4] = {};
  gemm_core_gl(A + (size_t)row0*HIDq, Bt + (size_t)col0*HIDq, As, Bs, t, wv, lane, wr, wc, lr, g, acc);
  #pragma unroll
  for (int n=0;n<4;n++){
    #pragma unroll
    for (int m=0;m<4;m++){
      int row = row0 + wr + m*16 + lr;
      int colb = col0 + wc + n*16 + g*4;
      f32x4 bb = *(const f32x4*)&bias[colb];
      f32x4 o = acc[n][m] + bb;
      *(f32x4*)&C[(size_t)row*HIDq + colb] = o;
    }
  }
}

// ------------- flash attention: 8 waves, q-tile 128, KVBLK 128, no-max softmax -------------
// scores are tiny (|sv_log2| <~ 30 worst-case): p = exp2(sv)*sigmoid(st) unnormalized,
// bf16 relative precision is scale-invariant; masked keys underflow to exactly 0.
__global__ __launch_bounds__(512,2) void attn_kernel(
    const unsigned short* __restrict__ Qe, const unsigned short* __restrict__ Ke,
    const unsigned short* __restrict__ Vt, const float* __restrict__ Tb,
    const float* __restrict__ tbias, const int* __restrict__ mask,
    unsigned short* __restrict__ Obuf)
{
  __shared__ __align__(16) unsigned char smem[49664];
  unsigned short* Ks = (unsigned short*)smem;             // [128 k][64 d] swizzled, 16 KB
  unsigned short* Vs = (unsigned short*)(smem + 16384);   // [64 d][128 k] swizzled, 16 KB
  unsigned short* Pl = (unsigned short*)(smem + 32768);   // 8 waves x [16 q][64 k], 16 KB
  float* mskf = (float*)(smem + 49152);                   // 128 f32
  float* qls = (float*)smem;                              // prologue overlay (16.9 KB, consumed pre-loop)
  unsigned short* qtls = Pl;                              // prologue overlay (10.2 KB <= 16 KB)

  const int t = threadIdx.x;
  // XCD-aware decode: all 16 q-blocks of a (b,h) land on one XCD
  const int dd = blockIdx.x;
  const int slot = dd>>3, xcd = dd&7;
  const int x = slot & 15;
  const int bh = ((slot>>4)<<3) | xcd;
  const int h = bh & 15, b = bh >> 4;
  const int q0 = x*128;
  const int wv = t>>6, lane = t&63, g = lane>>4, lr = lane&15;

  const unsigned short* Qb  = Qe + (((size_t)b*NHh+h)*Sq + q0)*HDq;
  const unsigned short* Kb  = Ke + ((size_t)b*NHh+h)*(size_t)Sq*HDq;
  const unsigned short* Vtb = Vt + ((size_t)b*NHh+h)*(size_t)HDq*Sq;
  const int* Mb = mask + (size_t)b*Sq;

  // ---- prefetch tile 0 into regs (T14) ----
  i32x4 kreg[2], vreg[2];
  #pragma unroll
  for (int i=0;i<2;i++){
    int c = t + i*512;
    int kr = c>>3, kc = (c&7)*8;
    kreg[i] = *(const i32x4*)(Kb + (size_t)kr*HDq + kc);
    int vd = c>>4, vc = (c&15)*8;
    vreg[i] = *(const i32x4*)(Vtb + (size_t)vd*Sq + vc);
  }
  int mv = (t<128) ? Mb[t] : 0;

  // ---- prologue: qt = q_type(-log2e-scaled) @ T[h] ----
  {
    int row = t>>2, c8 = (t&3)*8;
    bf16x8 v = *(const bf16x8*)(Qb + (size_t)row*HDq + 32 + c8);
    #pragma unroll
    for (int j=0;j<8;j++) qls[row*33 + c8 + j] = bf2f((unsigned short)v[j]);
  }
  __syncthreads();
  {
    int row = t&127, e0 = (t>>7)*8;
    const float* Th = Tb + (size_t)h*1024;
    float a[8] = {};
    #pragma unroll 4
    for (int d=0; d<32; d++){
      float qd = qls[row*33 + d];
      const f32x4* tp = (const f32x4*)(Th + d*32 + e0);
      f32x4 t0 = tp[0], t1 = tp[1];
      a[0]+=qd*t0[0]; a[1]+=qd*t0[1]; a[2]+=qd*t0[2]; a[3]+=qd*t0[3];
      a[4]+=qd*t1[0]; a[5]+=qd*t1[1]; a[6]+=qd*t1[2]; a[7]+=qd*t1[3];
    }
    union { unsigned u[2]; unsigned long long ll; } W0, W1;
    W0.u[0]=pk2bf(a[0],a[1]); W0.u[1]=pk2bf(a[2],a[3]);
    W1.u[0]=pk2bf(a[4],a[5]); W1.u[1]=pk2bf(a[6],a[7]);
    *(unsigned long long*)&qtls[row*40 + e0]     = W0.ll;
    *(unsigned long long*)&qtls[row*40 + e0 + 4] = W1.ll;
  }
  bf16x8 qvf = *(const bf16x8*)(Qb + (size_t)(wv*16+lr)*HDq + g*8);   // val half (prescaled)
  __syncthreads();
  bf16x8 qtn = *(const bf16x8*)&qtls[(wv*16+lr)*40 + g*8];            // type half (neg-scaled)

  const float tbn = -tbias[h]*LOG2E;
  const f32x4 tbc = {tbn,tbn,tbn,tbn};
  f32x4 oT[4] = {};
  f32x4 lsum = {0.f,0.f,0.f,0.f};
  unsigned short* Pw = &Pl[wv*1024 + lr*64];
  const int swp = (lr&7)*8;
  bf16x8 onesf;
  #pragma unroll
  for (int j=0;j<8;j++) onesf[j] = (short)0x3F80;

  for (int kt=0; kt<Sq; kt+=128){
    __syncthreads();
    #pragma unroll
    for (int i=0;i<2;i++){
      int c = t + i*512;
      int kr = c>>3, kc = (c&7)*8;
      *(i32x4*)&Ks[kr*64 + (kc ^ ((kr&7)*8))] = kreg[i];
      int vd = c>>4, vc = (c&15)*8;
      *(i32x4*)&Vs[vd*128 + (vc ^ ((vd&15)*8))] = vreg[i];
    }
    if (t<128) mskf[t] = mv ? 0.f : -1e30f;
    __syncthreads();
    if (kt + 128 < Sq){
      #pragma unroll
      for (int i=0;i<2;i++){
        int c = t + i*512;
        int kr = c>>3, kc = (c&7)*8;
        kreg[i] = *(const i32x4*)(Kb + (size_t)(kt+128+kr)*HDq + kc);
        int vd = c>>4, vc = (c&15)*8;
        vreg[i] = *(const i32x4*)(Vtb + (size_t)vd*Sq + kt + 128 + vc);
      }
      if (t<128) mv = Mb[kt+128+t];
    }

    #pragma unroll
    for (int kh=0; kh<2; kh++){
      // ---- QK^T swapped: lane holds S[q=lr][k = kh*64+16ks+4g+r] ----
      f32x4 sv[4], st[4];
      __builtin_amdgcn_s_setprio(1);
      #pragma unroll
      for (int ks=0; ks<4; ks++){
        int krow = kh*64 + ks*16 + lr;
        const unsigned short* kb = &Ks[krow*64];
        int sw = (krow&7)*8;
        bf16x8 kf0 = *(const bf16x8*)(kb + ((g*8) ^ sw));
        bf16x8 kf1 = *(const bf16x8*)(kb + ((32 + g*8) ^ sw));
        f32x4 madd = *(const f32x4*)&mskf[kh*64 + ks*16 + g*4];
        sv[ks] = __builtin_amdgcn_mfma_f32_16x16x32_bf16(kf0, qvf, madd, 0,0,0);
        st[ks] = __builtin_amdgcn_mfma_f32_16x16x32_bf16(kf1, qtn, tbc, 0,0,0);
      }
      __builtin_amdgcn_s_setprio(0);
      // ---- p = exp2(sv) * sigmoid (no max tracking; masked sv=-1e30 -> p=0) ----
      #pragma unroll
      for (int ks=0; ks<4; ks++){
        float p0 = EXP2F(sv[ks][0]) * RCPF(1.f + EXP2F(st[ks][0]));
        float p1 = EXP2F(sv[ks][1]) * RCPF(1.f + EXP2F(st[ks][1]));
        float p2 = EXP2F(sv[ks][2]) * RCPF(1.f + EXP2F(st[ks][2]));
        float p3 = EXP2F(sv[ks][3]) * RCPF(1.f + EXP2F(st[ks][3]));
        union { unsigned u[2]; unsigned long long ll; } W;
        W.u[0] = pk2bf(p0,p1); W.u[1] = pk2bf(p2,p3);
        *(unsigned long long*)(Pw + ((ks*16 + g*4) ^ swp)) = W.ll;
      }
      // ---- PV: oT[d][q] += V^T * P ; lsum via ones-MFMA ----
      #pragma unroll
      for (int ks2=0; ks2<2; ks2++){
        bf16x8 pf = *(const bf16x8*)(Pw + ((ks2*32 + g*8) ^ swp));
        __builtin_amdgcn_s_setprio(1);
        lsum = __builtin_amdgcn_mfma_f32_16x16x32_bf16(onesf, pf, lsum, 0,0,0);
        #pragma unroll
        for (int db=0; db<4; db++){
          int vrow = db*16 + lr;
          bf16x8 vf = *(const bf16x8*)(&Vs[vrow*128] + ((kh*64 + ks2*32 + g*8) ^ ((vrow&15)*8)));
          oT[db] = __builtin_amdgcn_mfma_f32_16x16x32_bf16(vf, pf, oT[db], 0,0,0);
        }
        __builtin_amdgcn_s_setprio(0);
      }
    }
  }

  // ---- epilogue: lane q = lr; oT[db][r] = O[d=db*16+4g+r][q] ----
  float linv = (lsum[0] > 0.f) ? RCPF(lsum[0]) : 0.f;
  int srow = q0 + wv*16 + lr;
  unsigned short* Ob = Obuf + ((size_t)b*Sq + srow)*HIDq + h*HDq;
  #pragma unroll
  for (int db=0; db<4; db++){
    union { unsigned u[2]; unsigned long long ll; } W;
    W.u[0] = pk2bf(oT[db][0]*linv, oT[db][1]*linv);
    W.u[1] = pk2bf(oT[db][2]*linv, oT[db][3]*linv);
    *(unsigned long long*)(Ob + db*16 + g*4) = W.ll;
  }
}

extern "C" void kernel_launch(void* const* d_in, const int* in_sizes, int n_in,
                              void* d_out, int out_size, void* d_ws, size_t ws_size,
                              hipStream_t stream) {
  const float* x     = (const float*)d_in[0];
  const float* q_w   = (const float*)d_in[1];
  const float* q_b   = (const float*)d_in[2];
  const float* k_w   = (const float*)d_in[3];
  const float* k_b   = (const float*)d_in[4];
  const float* v_w   = (const float*)d_in[5];
  const float* v_b   = (const float*)d_in[6];
  const float* out_w = (const float*)d_in[7];
  const float* out_b = (const float*)d_in[8];
  const float* Tb    = (const float*)d_in[9];
  const float* tbias = (const float*)d_in[10];
  const int*   mask  = (const int*)d_in[11];

  const size_t MROWS = 4096;             // B*S
  unsigned short* xbf  = (unsigned short*)d_ws;           // 4M shorts
  unsigned short* wT   = xbf  + MROWS*HIDq;               // 4 x 1M
  unsigned short* Qeff = wT   + (size_t)4*HIDq*HIDq;      // (B,NH,S,HD), prescaled
  unsigned short* Keff = Qeff + MROWS*HIDq;
  unsigned short* Vt   = Keff + MROWS*HIDq;               // (B,NH,HD,S) transposed
  unsigned short* Obuf = Vt   + MROWS*HIDq;               // (B,S,HID) bf16

  convert_x<<<dim3((int)(MROWS*HIDq/8/256)), dim3(256), 0, stream>>>(x, xbf, (int)(MROWS*HIDq/8));
  transpose_w<<<dim3(32,32,4), dim3(32,8), 0, stream>>>(q_w, k_w, v_w, out_w, wT);

  gemm_qkv<<<dim3(24,32), dim3(256), 0, stream>>>(xbf, wT, q_b, k_b, v_b, Qeff, Keff, Vt);

  attn_kernel<<<dim3(512), dim3(512), 0, stream>>>(Qeff, Keff, Vt, Tb, tbias, mask, Obuf);

  gemm_out<<<dim3(8,32), dim3(256), 0, stream>>>(Obuf, wT + (size_t)3*HIDq*HIDq, out_b, (float*)d_out);
}

// Round 7
// 170.909 us; speedup vs baseline: 2.1913x; 1.0164x over previous
//
#include <hip/hip_runtime.h>
#include <hip/hip_bf16.h>
#include <math.h>

typedef __attribute__((ext_vector_type(8))) short bf16x8;
typedef __attribute__((ext_vector_type(4))) float f32x4;
typedef __attribute__((ext_vector_type(4))) int   i32x4;

#define NHh 16
#define Sq  2048
#define HIDq 1024
#define HDq 64
#define LOG2E 1.4426950408889634f

#if __has_builtin(__builtin_amdgcn_exp2f)
#define EXP2F(x) __builtin_amdgcn_exp2f(x)
#else
#define EXP2F(x) exp2f(x)
#endif
#if __has_builtin(__builtin_amdgcn_rcpf)
#define RCPF(x) __builtin_amdgcn_rcpf(x)
#else
#define RCPF(x) (1.0f/(x))
#endif

__device__ __forceinline__ unsigned short f2bf(float f){
  union { float f; unsigned u; } v; v.f = f;
  unsigned r = v.u + 0x7fffu + ((v.u >> 16) & 1u);   // RNE
  return (unsigned short)(r >> 16);
}
__device__ __forceinline__ float bf2f(unsigned short s){
  union { unsigned u; float f; } v; v.u = ((unsigned)s) << 16;
  return v.f;
}
__device__ __forceinline__ unsigned pk2bf(float lo, float hi){
  union { __hip_bfloat162 h; unsigned u; } w;
  w.h = __float22bfloat162_rn(make_float2(lo, hi));
  return w.u;
}

// async global->LDS, 16B per lane; LDS dest = wave-uniform base + lane*16 (linear)
__device__ __forceinline__ void gload_lds16(const unsigned short* g, unsigned short* l){
  __builtin_amdgcn_global_load_lds(
      (const __attribute__((address_space(1))) unsigned int*)g,
      (__attribute__((address_space(3))) unsigned int*)l, 16, 0, 0);
}

// ---------------- convert x (f32 -> bf16) + mask -> f32 0/-1e30 tail ----------------
__global__ __launch_bounds__(256) void convert_x(const float* __restrict__ in,
                                                 unsigned short* __restrict__ out, int n8,
                                                 const int* __restrict__ mask,
                                                 float* __restrict__ Mf){
  int bid = blockIdx.x;
  int nmain = gridDim.x - 2;
  if (bid >= nmain){
    int base = (bid - nmain)*2048 + threadIdx.x*8;
    #pragma unroll
    for (int j=0;j<8;j++) Mf[base+j] = mask[base+j] ? 0.f : -1e30f;
    return;
  }
  int i = bid*256 + threadIdx.x;
  if (i >= n8) return;
  const f32x4* p = (const f32x4*)(in + (size_t)i*8);
  f32x4 a = p[0], b = p[1];
  union { unsigned short us[8]; i32x4 v; } o;
  #pragma unroll
  for (int j=0;j<4;j++){ o.us[j] = f2bf(a[j]); o.us[4+j] = f2bf(b[j]); }
  *(i32x4*)(out + (size_t)i*8) = o.v;
}

// ------------- transpose+convert weights: w[K][N] f32 -> wT[N][K] bf16 -------------
__global__ __launch_bounds__(256) void transpose_w(const float* __restrict__ w0, const float* __restrict__ w1,
                                                   const float* __restrict__ w2, const float* __restrict__ w3,
                                                   unsigned short* __restrict__ wT){
  __shared__ float tile[32][33];
  int z = blockIdx.z;
  const float* w = (z==0)?w0:(z==1)?w1:(z==2)?w2:w3;
  unsigned short* dst = wT + (size_t)z*HIDq*HIDq;
  int tx = threadIdx.x, ty = threadIdx.y;
  int n0 = blockIdx.x*32, k0 = blockIdx.y*32;
  #pragma unroll
  for (int i=ty;i<32;i+=8) tile[i][tx] = w[(size_t)(k0+i)*HIDq + n0+tx];
  __syncthreads();
  #pragma unroll
  for (int i=ty;i<32;i+=8) dst[(size_t)(n0+i)*HIDq + k0+tx] = f2bf(tile[tx][i]);
}

// ------------- GEMM main loop (R2-measured structure): BK=32, padded LDS, reg staging -------------
// acc[n][m] holds C[row = wr+m*16+lr][cols = wc+n*16+g*4 .. +3]
__device__ __forceinline__ void gemm_core(const unsigned short* __restrict__ Ag,
                                          const unsigned short* __restrict__ Bg,
                                          unsigned short* As, unsigned short* Bs,
                                          int t, int wr, int wc, int lr, int g,
                                          f32x4 acc[4][4]){
  for (int k0=0; k0<HIDq; k0+=32){
    __syncthreads();
    #pragma unroll
    for (int i=0;i<2;i++){
      int flat = t + i*256;
      int row = flat>>2, kc = (flat&3)*8;
      *(i32x4*)&As[row*40+kc] = *(const i32x4*)(Ag + (size_t)row*HIDq + k0 + kc);
      *(i32x4*)&Bs[row*40+kc] = *(const i32x4*)(Bg + (size_t)row*HIDq + k0 + kc);
    }
    __syncthreads();
    bf16x8 af[4], bfv[4];
    #pragma unroll
    for (int m=0;m<4;m++) af[m]  = *(bf16x8*)&As[(wr+m*16+lr)*40 + g*8];
    #pragma unroll
    for (int n=0;n<4;n++) bfv[n] = *(bf16x8*)&Bs[(wc+n*16+lr)*40 + g*8];
    #pragma unroll
    for (int n=0;n<4;n++)
      #pragma unroll
      for (int m=0;m<4;m++)
        acc[n][m] = __builtin_amdgcn_mfma_f32_16x16x32_bf16(bfv[n], af[m], acc[n][m], 0,0,0);
  }
}

// ------------- fused QKV projection -------------
__global__ __launch_bounds__(256) void gemm_qkv(const unsigned short* __restrict__ xbf,
    const unsigned short* __restrict__ wT,
    const float* __restrict__ q_b, const float* __restrict__ k_b, const float* __restrict__ v_b,
    unsigned short* __restrict__ Qeff, unsigned short* __restrict__ Keff,
    unsigned short* __restrict__ Vt){
  __shared__ unsigned short As[128*40];
  __shared__ unsigned short Bs[128*40];
  const int t = threadIdx.x;
  const int wv = t>>6, lane = t&63, g = lane>>4, lr = lane&15;
  const int wr = (wv>>1)*64, wc = (wv&1)*64;
  f32x4 acc[4][4] = {};
  const int xb = blockIdx.x, yb = blockIdx.y;
  const float VS = 0.25501335f;   // log2e / sqrt(32)

  if (xb < 16){
    const int row0 = yb*128, col0 = xb*128;
    gemm_core(xbf + (size_t)row0*HIDq, wT + (size_t)col0*HIDq, As, Bs, t, wr, wc, lr, g, acc);
    #pragma unroll
    for (int n=0;n<4;n++){
      #pragma unroll
      for (int m=0;m<4;m++){
        int row = row0 + wr + m*16 + lr;
        int b_ = row>>11, ss = row&2047;
        int colb = col0 + wc + n*16 + g*4;
        int seg = colb>>10, cw = colb&1023;
        int hh = cw>>6, d = cw&63;
        const float* bp = seg ? k_b : q_b;
        f32x4 bb = *(const f32x4*)&bp[cw];
        float sc = seg ? 1.0f : (d < 32 ? VS : -LOG2E);
        unsigned short* E = seg ? Keff : Qeff;
        float v0 = (acc[n][m][0]+bb[0])*sc, v1 = (acc[n][m][1]+bb[1])*sc;
        float v2 = (acc[n][m][2]+bb[2])*sc, v3 = (acc[n][m][3]+bb[3])*sc;
        union { unsigned u[2]; unsigned long long ll; } W;
        W.u[0] = pk2bf(v0,v1); W.u[1] = pk2bf(v2,v3);
        *(unsigned long long*)&E[(((size_t)b_*NHh+hh)*Sq+ss)*HDq + d] = W.ll;
      }
    }
  } else {
    const int row0 = (xb-16)*128, col0 = yb*128;
    gemm_core(wT + (size_t)2*HIDq*HIDq + (size_t)row0*HIDq, xbf + (size_t)col0*HIDq,
              As, Bs, t, wr, wc, lr, g, acc);
    #pragma unroll
    for (int n=0;n<4;n++){
      #pragma unroll
      for (int m=0;m<4;m++){
        int chan = row0 + wr + m*16 + lr;
        int hh = chan>>6, d = chan&63;
        float bv = v_b[chan];
        int colb = col0 + wc + n*16 + g*4;
        int b_ = colb>>11, ss = colb&2047;
        union { unsigned u[2]; unsigned long long ll; } W;
        W.u[0] = pk2bf(acc[n][m][0]+bv, acc[n][m][1]+bv);
        W.u[1] = pk2bf(acc[n][m][2]+bv, acc[n][m][3]+bv);
        *(unsigned long long*)&Vt[(((size_t)b_*NHh+hh)*HDq + d)*Sq + ss] = W.ll;
      }
    }
  }
}

// ------------- output projection: C f32 = A@Bt^T + bias -------------
__global__ __launch_bounds__(256) void gemm_out(const unsigned short* __restrict__ A,
                                                const unsigned short* __restrict__ Bt,
                                                const float* __restrict__ bias,
                                                float* __restrict__ C){
  __shared__ unsigned short As[128*40];
  __shared__ unsigned short Bs[128*40];
  const int t = threadIdx.x;
  const int wv = t>>6, lane = t&63, g = lane>>4, lr = lane&15;
  const int wr = (wv>>1)*64, wc = (wv&1)*64;
  const int row0 = blockIdx.y*128, col0 = blockIdx.x*128;
  f32x4 acc[4][4] = {};
  gemm_core(A + (size_t)row0*HIDq, Bt + (size_t)col0*HIDq, As, Bs, t, wr, wc, lr, g, acc);
  #pragma unroll
  for (int n=0;n<4;n++){
    #pragma unroll
    for (int m=0;m<4;m++){
      int row = row0 + wr + m*16 + lr;
      int colb = col0 + wc + n*16 + g*4;
      f32x4 bb = *(const f32x4*)&bias[colb];
      f32x4 o = acc[n][m] + bb;
      *(f32x4*)&C[(size_t)row*HIDq + colb] = o;
    }
  }
}

// ------------- flash attention: 8 waves, q-tile 128, KVBLK 128, K/V dbuf + gload_lds -------------
// Layout: Ks0 @0, Vs0 @16384, Ks1 @32768, Vs1 @49152, Pl @65536..81920 (80 KB total)
// no-max softmax: p = exp2(sv)*sigmoid2(st); masked keys get sv=-1e30 (via MFMA C-init) -> p=0.
__global__ __launch_bounds__(512,2) void attn_kernel(
    const unsigned short* __restrict__ Qe, const unsigned short* __restrict__ Ke,
    const unsigned short* __restrict__ Vt, const float* __restrict__ Tb,
    const float* __restrict__ tbias, const float* __restrict__ Mf,
    unsigned short* __restrict__ Obuf)
{
  __shared__ __align__(16) unsigned char smem[81920];
  unsigned short* Ks0 = (unsigned short*)smem;
  unsigned short* Vs0 = (unsigned short*)(smem + 16384);
  unsigned short* Ks1 = (unsigned short*)(smem + 32768);
  unsigned short* Vs1 = (unsigned short*)(smem + 49152);
  unsigned short* Pl  = (unsigned short*)(smem + 65536);
  float* qls = (float*)(smem + 32768);            // overlay: Ks1 + 512B of Vs1, pre-loop only
  unsigned short* qtls = Pl;                      // overlay: consumed before first P write (extra barrier)

  const int t = threadIdx.x;
  // XCD-aware decode: all 16 q-blocks of a (b,h) land on one XCD
  const int dd = blockIdx.x;
  const int slot = dd>>3, xcd = dd&7;
  const int x = slot & 15;
  const int bh = ((slot>>4)<<3) | xcd;
  const int h = bh & 15, b = bh >> 4;
  const int q0 = x*128;
  const int wv = t>>6, lane = t&63, g = lane>>4, lr = lane&15;

  const unsigned short* Qb  = Qe + (((size_t)b*NHh+h)*Sq + q0)*HDq;
  const unsigned short* Kb  = Ke + ((size_t)b*NHh+h)*(size_t)Sq*HDq;
  const unsigned short* Vtb = Vt + ((size_t)b*NHh+h)*(size_t)HDq*Sq;
  const float* Mfb = Mf + (size_t)b*Sq;

  // chunk geometry for staging (16B chunks): per thread 2 K-chunks + 2 V-chunks
  const int ch0 = (wv*2+0)*64 + lane, ch1 = (wv*2+1)*64 + lane;

  // ---- stage tile 0 into buf0 (lands by first barrier) ----
  {
    int kr0 = ch0>>3, kc0 = ch0&7, kr1 = ch1>>3, kc1 = ch1&7;
    gload_lds16(Kb + (size_t)kr0*HDq + (kc0 ^ (kr0&7))*8, Ks0 + ch0*8);
    gload_lds16(Kb + (size_t)kr1*HDq + (kc1 ^ (kr1&7))*8, Ks0 + ch1*8);
    int vd0 = ch0>>4, vc0 = ch0&15, vd1 = ch1>>4, vc1 = ch1&15;
    gload_lds16(Vtb + (size_t)vd0*Sq + (vc0 ^ (vd0&15))*8, Vs0 + ch0*8);
    gload_lds16(Vtb + (size_t)vd1*Sq + (vc1 ^ (vd1&15))*8, Vs0 + ch1*8);
  }

  // ---- prologue: qt = q_type(-log2e-scaled) @ T[h] ----
  {
    int row = t>>2, c8 = (t&3)*8;
    bf16x8 v = *(const bf16x8*)(Qb + (size_t)row*HDq + 32 + c8);
    #pragma unroll
    for (int j=0;j<8;j++) qls[row*33 + c8 + j] = bf2f((unsigned short)v[j]);
  }
  __syncthreads();
  {
    int row = t&127, e0 = (t>>7)*8;
    const float* Th = Tb + (size_t)h*1024;
    float a[8] = {};
    #pragma unroll 4
    for (int d=0; d<32; d++){
      float qd = qls[row*33 + d];
      const f32x4* tp = (const f32x4*)(Th + d*32 + e0);
      f32x4 t0 = tp[0], t1 = tp[1];
      a[0]+=qd*t0[0]; a[1]+=qd*t0[1]; a[2]+=qd*t0[2]; a[3]+=qd*t0[3];
      a[4]+=qd*t1[0]; a[5]+=qd*t1[1]; a[6]+=qd*t1[2]; a[7]+=qd*t1[3];
    }
    __syncthreads();   // all qls reads done before qtls (in Pl) written & Ks1/Vs1 reused
    union { unsigned u[2]; unsigned long long ll; } W0, W1;
    W0.u[0]=pk2bf(a[0],a[1]); W0.u[1]=pk2bf(a[2],a[3]);
    W1.u[0]=pk2bf(a[4],a[5]); W1.u[1]=pk2bf(a[6],a[7]);
    *(unsigned long long*)&qtls[row*40 + e0]     = W0.ll;
    *(unsigned long long*)&qtls[row*40 + e0 + 4] = W1.ll;
  }
  bf16x8 qvf = *(const bf16x8*)(Qb + (size_t)(wv*16+lr)*HDq + g*8);   // val half (prescaled)
  __syncthreads();
  bf16x8 qtn = *(const bf16x8*)&qtls[(wv*16+lr)*40 + g*8];            // type half (neg-scaled)
  __syncthreads();   // qtn reads complete before Pl used for P

  const float tbn = -tbias[h]*LOG2E;
  const f32x4 tbc = {tbn,tbn,tbn,tbn};
  f32x4 oT[4] = {};
  f32x4 lsum = {0.f,0.f,0.f,0.f};
  unsigned short* Pw = &Pl[wv*1024 + lr*64];
  const int swp = (lr&7)*8;
  bf16x8 onesf;
  #pragma unroll
  for (int j=0;j<8;j++) onesf[j] = (short)0x3F80;

  unsigned short *Kc = Ks0, *Vc = Vs0, *Kn = Ks1, *Vn = Vs1;

  for (int kt=0; kt<Sq; kt+=128){
    // mask adds for this tile (loaded BEFORE staging so their wait doesn't drain staging queue)
    f32x4 madd[2][4];
    #pragma unroll
    for (int kh2=0; kh2<2; kh2++)
      #pragma unroll
      for (int ks=0; ks<4; ks++)
        madd[kh2][ks] = *(const f32x4*)(Mfb + kt + kh2*64 + ks*16 + g*4);
    // stage next tile into the other buffer; lands by end-of-iter barrier
    if (kt + 128 < Sq){
      int kt2 = kt + 128;
      int kr0 = ch0>>3, kc0 = ch0&7, kr1 = ch1>>3, kc1 = ch1&7;
      gload_lds16(Kb + (size_t)(kt2+kr0)*HDq + (kc0 ^ (kr0&7))*8, Kn + ch0*8);
      gload_lds16(Kb + (size_t)(kt2+kr1)*HDq + (kc1 ^ (kr1&7))*8, Kn + ch1*8);
      int vd0 = ch0>>4, vc0 = ch0&15, vd1 = ch1>>4, vc1 = ch1&15;
      gload_lds16(Vtb + (size_t)vd0*Sq + kt2 + (vc0 ^ (vd0&15))*8, Vn + ch0*8);
      gload_lds16(Vtb + (size_t)vd1*Sq + kt2 + (vc1 ^ (vd1&15))*8, Vn + ch1*8);
    }

    #pragma unroll
    for (int kh=0; kh<2; kh++){
      // ---- QK^T swapped: lane holds S[q=lr][k = kh*64+16ks+4g+r]; mask/bias in C-init ----
      f32x4 sv[4], st[4];
      __builtin_amdgcn_s_setprio(1);
      #pragma unroll
      for (int ks=0; ks<4; ks++){
        int krow = kh*64 + ks*16 + lr;
        const unsigned short* kb = &Kc[krow*64];
        int sw = (krow&7)*8;
        bf16x8 kf0 = *(const bf16x8*)(kb + ((g*8) ^ sw));
        bf16x8 kf1 = *(const bf16x8*)(kb + ((32 + g*8) ^ sw));
        sv[ks] = __builtin_amdgcn_mfma_f32_16x16x32_bf16(kf0, qvf, madd[kh][ks], 0,0,0);
        st[ks] = __builtin_amdgcn_mfma_f32_16x16x32_bf16(kf1, qtn, tbc, 0,0,0);
      }
      __builtin_amdgcn_s_setprio(0);
      // ---- p = exp2(sv) * sigmoid2(st) ----
      #pragma unroll
      for (int ks=0; ks<4; ks++){
        float p0 = EXP2F(sv[ks][0]) * RCPF(1.f + EXP2F(st[ks][0]));
        float p1 = EXP2F(sv[ks][1]) * RCPF(1.f + EXP2F(st[ks][1]));
        float p2 = EXP2F(sv[ks][2]) * RCPF(1.f + EXP2F(st[ks][2]));
        float p3 = EXP2F(sv[ks][3]) * RCPF(1.f + EXP2F(st[ks][3]));
        union { unsigned u[2]; unsigned long long ll; } W;
        W.u[0] = pk2bf(p0,p1); W.u[1] = pk2bf(p2,p3);
        *(unsigned long long*)(Pw + ((ks*16 + g*4) ^ swp)) = W.ll;
      }
      // ---- PV: oT[d][q] += V^T * P ; lsum via ones-MFMA ----
      #pragma unroll
      for (int ks2=0; ks2<2; ks2++){
        bf16x8 pf = *(const bf16x8*)(Pw + ((ks2*32 + g*8) ^ swp));
        __builtin_amdgcn_s_setprio(1);
        lsum = __builtin_amdgcn_mfma_f32_16x16x32_bf16(onesf, pf, lsum, 0,0,0);
        #pragma unroll
        for (int db=0; db<4; db++){
          int vrow = db*16 + lr;
          bf16x8 vf = *(const bf16x8*)(&Vc[vrow*128] + ((kh*64 + ks2*32 + g*8) ^ ((vrow&15)*8)));
          oT[db] = __builtin_amdgcn_mfma_f32_16x16x32_bf16(vf, pf, oT[db], 0,0,0);
        }
        __builtin_amdgcn_s_setprio(0);
      }
    }
    __syncthreads();   // staging drained + P/LDS reads done; swap buffers
    unsigned short* tp;
    tp = Kc; Kc = Kn; Kn = tp;
    tp = Vc; Vc = Vn; Vn = tp;
  }

  // ---- epilogue: lane q = lr; oT[db][r] = O[d=db*16+4g+r][q] ----
  float linv = (lsum[0] > 0.f) ? RCPF(lsum[0]) : 0.f;
  int srow = q0 + wv*16 + lr;
  unsigned short* Ob = Obuf + ((size_t)b*Sq + srow)*HIDq + h*HDq;
  #pragma unroll
  for (int db=0; db<4; db++){
    union { unsigned u[2]; unsigned long long ll; } W;
    W.u[0] = pk2bf(oT[db][0]*linv, oT[db][1]*linv);
    W.u[1] = pk2bf(oT[db][2]*linv, oT[db][3]*linv);
    *(unsigned long long*)(Ob + db*16 + g*4) = W.ll;
  }
}

extern "C" void kernel_launch(void* const* d_in, const int* in_sizes, int n_in,
                              void* d_out, int out_size, void* d_ws, size_t ws_size,
                              hipStream_t stream) {
  const float* x     = (const float*)d_in[0];
  const float* q_w   = (const float*)d_in[1];
  const float* q_b   = (const float*)d_in[2];
  const float* k_w   = (const float*)d_in[3];
  const float* k_b   = (const float*)d_in[4];
  const float* v_w   = (const float*)d_in[5];
  const float* v_b   = (const float*)d_in[6];
  const float* out_w = (const float*)d_in[7];
  const float* out_b = (const float*)d_in[8];
  const float* Tb    = (const float*)d_in[9];
  const float* tbias = (const float*)d_in[10];
  const int*   mask  = (const int*)d_in[11];

  const size_t MROWS = 4096;             // B*S
  unsigned short* xbf  = (unsigned short*)d_ws;           // 4M shorts
  unsigned short* wT   = xbf  + MROWS*HIDq;               // 4 x 1M
  unsigned short* Qeff = wT   + (size_t)4*HIDq*HIDq;      // (B,NH,S,HD), prescaled
  unsigned short* Keff = Qeff + MROWS*HIDq;
  unsigned short* Vt   = Keff + MROWS*HIDq;               // (B,NH,HD,S) transposed
  unsigned short* Obuf = Vt   + MROWS*HIDq;               // (B,S,HID) bf16
  float*          Mf   = (float*)(Obuf + MROWS*HIDq);     // (B,S) f32 mask adds, 16 KB

  int n8 = (int)(MROWS*HIDq/8);
  convert_x<<<dim3(n8/256 + 2), dim3(256), 0, stream>>>(x, xbf, n8, mask, Mf);
  transpose_w<<<dim3(32,32,4), dim3(32,8), 0, stream>>>(q_w, k_w, v_w, out_w, wT);

  gemm_qkv<<<dim3(24,32), dim3(256), 0, stream>>>(xbf, wT, q_b, k_b, v_b, Qeff, Keff, Vt);

  attn_kernel<<<dim3(512), dim3(512), 0, stream>>>(Qeff, Keff, Vt, Tb, tbias, Mf, Obuf);

  gemm_out<<<dim3(8,32), dim3(256), 0, stream>>>(Obuf, wT + (size_t)3*HIDq*HIDq, out_b, (float*)d_out);
}

// Round 8
// 159.637 us; speedup vs baseline: 2.3460x; 1.0706x over previous
//
#include <hip/hip_runtime.h>
#include <hip/hip_bf16.h>
#include <math.h>

typedef __attribute__((ext_vector_type(8))) short bf16x8;
typedef __attribute__((ext_vector_type(4))) float f32x4;
typedef __attribute__((ext_vector_type(4))) int   i32x4;

#define NHh 16
#define Sq  2048
#define HIDq 1024
#define HDq 64
#define LOG2E 1.4426950408889634f

#if __has_builtin(__builtin_amdgcn_exp2f)
#define EXP2F(x) __builtin_amdgcn_exp2f(x)
#else
#define EXP2F(x) exp2f(x)
#endif
#if __has_builtin(__builtin_amdgcn_rcpf)
#define RCPF(x) __builtin_amdgcn_rcpf(x)
#else
#define RCPF(x) (1.0f/(x))
#endif

__device__ __forceinline__ unsigned short f2bf(float f){
  union { float f; unsigned u; } v; v.f = f;
  unsigned r = v.u + 0x7fffu + ((v.u >> 16) & 1u);   // RNE
  return (unsigned short)(r >> 16);
}
__device__ __forceinline__ float bf2f(unsigned short s){
  union { unsigned u; float f; } v; v.u = ((unsigned)s) << 16;
  return v.f;
}
__device__ __forceinline__ unsigned pk2bf(float lo, float hi){
  union { __hip_bfloat162 h; unsigned u; } w;
  w.h = __float22bfloat162_rn(make_float2(lo, hi));
  return w.u;
}

// async global->LDS, 16B per lane; LDS dest = wave-uniform base + lane*16 (linear)
__device__ __forceinline__ void gload_lds16(const unsigned short* g, unsigned short* l){
  __builtin_amdgcn_global_load_lds(
      (const __attribute__((address_space(1))) unsigned int*)g,
      (__attribute__((address_space(3))) unsigned int*)l, 16, 0, 0);
}

// ---------------- convert x (f32 -> bf16) + mask -> f32 0/-1e30 tail ----------------
__global__ __launch_bounds__(256) void convert_x(const float* __restrict__ in,
                                                 unsigned short* __restrict__ out, int n8,
                                                 const int* __restrict__ mask,
                                                 float* __restrict__ Mf){
  int bid = blockIdx.x;
  int nmain = gridDim.x - 2;
  if (bid >= nmain){
    int base = (bid - nmain)*2048 + threadIdx.x*8;
    #pragma unroll
    for (int j=0;j<8;j++) Mf[base+j] = mask[base+j] ? 0.f : -1e30f;
    return;
  }
  int i = bid*256 + threadIdx.x;
  if (i >= n8) return;
  const f32x4* p = (const f32x4*)(in + (size_t)i*8);
  f32x4 a = p[0], b = p[1];
  union { unsigned short us[8]; i32x4 v; } o;
  #pragma unroll
  for (int j=0;j<4;j++){ o.us[j] = f2bf(a[j]); o.us[4+j] = f2bf(b[j]); }
  *(i32x4*)(out + (size_t)i*8) = o.v;
}

// ------------- transpose+convert weights: w[K][N] f32 -> wT[N][K] bf16 -------------
__global__ __launch_bounds__(256) void transpose_w(const float* __restrict__ w0, const float* __restrict__ w1,
                                                   const float* __restrict__ w2, const float* __restrict__ w3,
                                                   unsigned short* __restrict__ wT){
  __shared__ float tile[32][33];
  int z = blockIdx.z;
  const float* w = (z==0)?w0:(z==1)?w1:(z==2)?w2:w3;
  unsigned short* dst = wT + (size_t)z*HIDq*HIDq;
  int tx = threadIdx.x, ty = threadIdx.y;
  int n0 = blockIdx.x*32, k0 = blockIdx.y*32;
  #pragma unroll
  for (int i=ty;i<32;i+=8) tile[i][tx] = w[(size_t)(k0+i)*HIDq + n0+tx];
  __syncthreads();
  #pragma unroll
  for (int i=ty;i<32;i+=8) dst[(size_t)(n0+i)*HIDq + k0+tx] = f2bf(tile[tx][i]);
}

// ------------- GEMM main loop: gload_lds, BK=64, granule-XOR swizzled LDS (T2) -------------
// LDS tile [128 rows][8 granules of 8]; granule c of row r stored at c^(r&7).
// Global source pre-swizzled; ds_read applies same XOR -> lanes 0-7 hit 8 distinct
// bank-quads (conflict-free), lanes 8-15 alias 2-way (free).
// acc[n][m] holds C[row = wr+m*16+lr][cols = wc+n*16+g*4 .. +3]
__device__ __forceinline__ void gemm_core_gl(const unsigned short* __restrict__ Ag,
                                             const unsigned short* __restrict__ Bg,
                                             unsigned short* As, unsigned short* Bs,
                                             int t, int wv, int lane, int wr, int wc, int lr, int g,
                                             f32x4 acc[4][4]){
  for (int k0=0; k0<HIDq; k0+=64){
    __syncthreads();
    #pragma unroll
    for (int j=0;j<4;j++){
      int flat = (j*4+wv)*64 + lane;      // 0..1023, wave-uniform LDS base + lane*16
      int row = flat>>3, c = flat&7;
      int srcc = (c ^ (row&7))*8;
      gload_lds16(Ag + (size_t)row*HIDq + k0 + srcc, &As[flat*8]);
      gload_lds16(Bg + (size_t)row*HIDq + k0 + srcc, &Bs[flat*8]);
    }
    __syncthreads();
    #pragma unroll
    for (int ks=0; ks<2; ks++){
      bf16x8 af[4], bfv[4];
      #pragma unroll
      for (int m=0;m<4;m++){
        int rr = wr + m*16 + lr;
        af[m]  = *(bf16x8*)&As[rr*64 + (((ks*4+g) ^ (rr&7))*8)];
      }
      #pragma unroll
      for (int n=0;n<4;n++){
        int rr = wc + n*16 + lr;
        bfv[n] = *(bf16x8*)&Bs[rr*64 + (((ks*4+g) ^ (rr&7))*8)];
      }
      #pragma unroll
      for (int n=0;n<4;n++)
        #pragma unroll
        for (int m=0;m<4;m++)
          acc[n][m] = __builtin_amdgcn_mfma_f32_16x16x32_bf16(bfv[n], af[m], acc[n][m], 0,0,0);
    }
  }
}

// ------------- fused QKV projection -------------
__global__ __launch_bounds__(256) void gemm_qkv(const unsigned short* __restrict__ xbf,
    const unsigned short* __restrict__ wT,
    const float* __restrict__ q_b, const float* __restrict__ k_b, const float* __restrict__ v_b,
    unsigned short* __restrict__ Qeff, unsigned short* __restrict__ Keff,
    unsigned short* __restrict__ Vt){
  __shared__ unsigned short As[128*64];
  __shared__ unsigned short Bs[128*64];
  const int t = threadIdx.x;
  const int wv = t>>6, lane = t&63, g = lane>>4, lr = lane&15;
  const int wr = (wv>>1)*64, wc = (wv&1)*64;
  f32x4 acc[4][4] = {};
  const int xb = blockIdx.x, yb = blockIdx.y;
  const float VS = 0.25501335f;   // log2e / sqrt(32)

  if (xb < 16){
    const int row0 = yb*128, col0 = xb*128;
    gemm_core_gl(xbf + (size_t)row0*HIDq, wT + (size_t)col0*HIDq, As, Bs, t, wv, lane, wr, wc, lr, g, acc);
    #pragma unroll
    for (int n=0;n<4;n++){
      #pragma unroll
      for (int m=0;m<4;m++){
        int row = row0 + wr + m*16 + lr;
        int b_ = row>>11, ss = row&2047;
        int colb = col0 + wc + n*16 + g*4;
        int seg = colb>>10, cw = colb&1023;
        int hh = cw>>6, d = cw&63;
        const float* bp = seg ? k_b : q_b;
        f32x4 bb = *(const f32x4*)&bp[cw];
        float sc = seg ? 1.0f : (d < 32 ? VS : -LOG2E);
        unsigned short* E = seg ? Keff : Qeff;
        float v0 = (acc[n][m][0]+bb[0])*sc, v1 = (acc[n][m][1]+bb[1])*sc;
        float v2 = (acc[n][m][2]+bb[2])*sc, v3 = (acc[n][m][3]+bb[3])*sc;
        union { unsigned u[2]; unsigned long long ll; } W;
        W.u[0] = pk2bf(v0,v1); W.u[1] = pk2bf(v2,v3);
        *(unsigned long long*)&E[(((size_t)b_*NHh+hh)*Sq+ss)*HDq + d] = W.ll;
      }
    }
  } else {
    const int row0 = (xb-16)*128, col0 = yb*128;
    gemm_core_gl(wT + (size_t)2*HIDq*HIDq + (size_t)row0*HIDq, xbf + (size_t)col0*HIDq,
                 As, Bs, t, wv, lane, wr, wc, lr, g, acc);
    #pragma unroll
    for (int n=0;n<4;n++){
      #pragma unroll
      for (int m=0;m<4;m++){
        int chan = row0 + wr + m*16 + lr;
        int hh = chan>>6, d = chan&63;
        float bv = v_b[chan];
        int colb = col0 + wc + n*16 + g*4;
        int b_ = colb>>11, ss = colb&2047;
        union { unsigned u[2]; unsigned long long ll; } W;
        W.u[0] = pk2bf(acc[n][m][0]+bv, acc[n][m][1]+bv);
        W.u[1] = pk2bf(acc[n][m][2]+bv, acc[n][m][3]+bv);
        *(unsigned long long*)&Vt[(((size_t)b_*NHh+hh)*HDq + d)*Sq + ss] = W.ll;
      }
    }
  }
}

// ------------- output projection: C f32 = A@Bt^T + bias -------------
__global__ __launch_bounds__(256) void gemm_out(const unsigned short* __restrict__ A,
                                                const unsigned short* __restrict__ Bt,
                                                const float* __restrict__ bias,
                                                float* __restrict__ C){
  __shared__ unsigned short As[128*64];
  __shared__ unsigned short Bs[128*64];
  const int t = threadIdx.x;
  const int wv = t>>6, lane = t&63, g = lane>>4, lr = lane&15;
  const int wr = (wv>>1)*64, wc = (wv&1)*64;
  const int row0 = blockIdx.y*128, col0 = blockIdx.x*128;
  f32x4 acc[4][4] = {};
  gemm_core_gl(A + (size_t)row0*HIDq, Bt + (size_t)col0*HIDq, As, Bs, t, wv, lane, wr, wc, lr, g, acc);
  #pragma unroll
  for (int n=0;n<4;n++){
    #pragma unroll
    for (int m=0;m<4;m++){
      int row = row0 + wr + m*16 + lr;
      int colb = col0 + wc + n*16 + g*4;
      f32x4 bb = *(const f32x4*)&bias[colb];
      f32x4 o = acc[n][m] + bb;
      *(f32x4*)&C[(size_t)row*HIDq + colb] = o;
    }
  }
}

// ------------- flash attention: unchanged from R7 (verified) -------------
__global__ __launch_bounds__(512,2) void attn_kernel(
    const unsigned short* __restrict__ Qe, const unsigned short* __restrict__ Ke,
    const unsigned short* __restrict__ Vt, const float* __restrict__ Tb,
    const float* __restrict__ tbias, const float* __restrict__ Mf,
    unsigned short* __restrict__ Obuf)
{
  __shared__ __align__(16) unsigned char smem[81920];
  unsigned short* Ks0 = (unsigned short*)smem;
  unsigned short* Vs0 = (unsigned short*)(smem + 16384);
  unsigned short* Ks1 = (unsigned short*)(smem + 32768);
  unsigned short* Vs1 = (unsigned short*)(smem + 49152);
  unsigned short* Pl  = (unsigned short*)(smem + 65536);
  float* qls = (float*)(smem + 32768);
  unsigned short* qtls = Pl;

  const int t = threadIdx.x;
  const int dd = blockIdx.x;
  const int slot = dd>>3, xcd = dd&7;
  const int x = slot & 15;
  const int bh = ((slot>>4)<<3) | xcd;
  const int h = bh & 15, b = bh >> 4;
  const int q0 = x*128;
  const int wv = t>>6, lane = t&63, g = lane>>4, lr = lane&15;

  const unsigned short* Qb  = Qe + (((size_t)b*NHh+h)*Sq + q0)*HDq;
  const unsigned short* Kb  = Ke + ((size_t)b*NHh+h)*(size_t)Sq*HDq;
  const unsigned short* Vtb = Vt + ((size_t)b*NHh+h)*(size_t)HDq*Sq;
  const float* Mfb = Mf + (size_t)b*Sq;

  const int ch0 = (wv*2+0)*64 + lane, ch1 = (wv*2+1)*64 + lane;

  {
    int kr0 = ch0>>3, kc0 = ch0&7, kr1 = ch1>>3, kc1 = ch1&7;
    gload_lds16(Kb + (size_t)kr0*HDq + (kc0 ^ (kr0&7))*8, Ks0 + ch0*8);
    gload_lds16(Kb + (size_t)kr1*HDq + (kc1 ^ (kr1&7))*8, Ks0 + ch1*8);
    int vd0 = ch0>>4, vc0 = ch0&15, vd1 = ch1>>4, vc1 = ch1&15;
    gload_lds16(Vtb + (size_t)vd0*Sq + (vc0 ^ (vd0&15))*8, Vs0 + ch0*8);
    gload_lds16(Vtb + (size_t)vd1*Sq + (vc1 ^ (vd1&15))*8, Vs0 + ch1*8);
  }

  {
    int row = t>>2, c8 = (t&3)*8;
    bf16x8 v = *(const bf16x8*)(Qb + (size_t)row*HDq + 32 + c8);
    #pragma unroll
    for (int j=0;j<8;j++) qls[row*33 + c8 + j] = bf2f((unsigned short)v[j]);
  }
  __syncthreads();
  {
    int row = t&127, e0 = (t>>7)*8;
    const float* Th = Tb + (size_t)h*1024;
    float a[8] = {};
    #pragma unroll 4
    for (int d=0; d<32; d++){
      float qd = qls[row*33 + d];
      const f32x4* tp = (const f32x4*)(Th + d*32 + e0);
      f32x4 t0 = tp[0], t1 = tp[1];
      a[0]+=qd*t0[0]; a[1]+=qd*t0[1]; a[2]+=qd*t0[2]; a[3]+=qd*t0[3];
      a[4]+=qd*t1[0]; a[5]+=qd*t1[1]; a[6]+=qd*t1[2]; a[7]+=qd*t1[3];
    }
    __syncthreads();
    union { unsigned u[2]; unsigned long long ll; } W0, W1;
    W0.u[0]=pk2bf(a[0],a[1]); W0.u[1]=pk2bf(a[2],a[3]);
    W1.u[0]=pk2bf(a[4],a[5]); W1.u[1]=pk2bf(a[6],a[7]);
    *(unsigned long long*)&qtls[row*40 + e0]     = W0.ll;
    *(unsigned long long*)&qtls[row*40 + e0 + 4] = W1.ll;
  }
  bf16x8 qvf = *(const bf16x8*)(Qb + (size_t)(wv*16+lr)*HDq + g*8);
  __syncthreads();
  bf16x8 qtn = *(const bf16x8*)&qtls[(wv*16+lr)*40 + g*8];
  __syncthreads();

  const float tbn = -tbias[h]*LOG2E;
  const f32x4 tbc = {tbn,tbn,tbn,tbn};
  f32x4 oT[4] = {};
  f32x4 lsum = {0.f,0.f,0.f,0.f};
  unsigned short* Pw = &Pl[wv*1024 + lr*64];
  const int swp = (lr&7)*8;
  bf16x8 onesf;
  #pragma unroll
  for (int j=0;j<8;j++) onesf[j] = (short)0x3F80;

  unsigned short *Kc = Ks0, *Vc = Vs0, *Kn = Ks1, *Vn = Vs1;

  for (int kt=0; kt<Sq; kt+=128){
    f32x4 madd[2][4];
    #pragma unroll
    for (int kh2=0; kh2<2; kh2++)
      #pragma unroll
      for (int ks=0; ks<4; ks++)
        madd[kh2][ks] = *(const f32x4*)(Mfb + kt + kh2*64 + ks*16 + g*4);
    if (kt + 128 < Sq){
      int kt2 = kt + 128;
      int kr0 = ch0>>3, kc0 = ch0&7, kr1 = ch1>>3, kc1 = ch1&7;
      gload_lds16(Kb + (size_t)(kt2+kr0)*HDq + (kc0 ^ (kr0&7))*8, Kn + ch0*8);
      gload_lds16(Kb + (size_t)(kt2+kr1)*HDq + (kc1 ^ (kr1&7))*8, Kn + ch1*8);
      int vd0 = ch0>>4, vc0 = ch0&15, vd1 = ch1>>4, vc1 = ch1&15;
      gload_lds16(Vtb + (size_t)vd0*Sq + kt2 + (vc0 ^ (vd0&15))*8, Vn + ch0*8);
      gload_lds16(Vtb + (size_t)vd1*Sq + kt2 + (vc1 ^ (vd1&15))*8, Vn + ch1*8);
    }

    #pragma unroll
    for (int kh=0; kh<2; kh++){
      f32x4 sv[4], st[4];
      __builtin_amdgcn_s_setprio(1);
      #pragma unroll
      for (int ks=0; ks<4; ks++){
        int krow = kh*64 + ks*16 + lr;
        const unsigned short* kb = &Kc[krow*64];
        int sw = (krow&7)*8;
        bf16x8 kf0 = *(const bf16x8*)(kb + ((g*8) ^ sw));
        bf16x8 kf1 = *(const bf16x8*)(kb + ((32 + g*8) ^ sw));
        sv[ks] = __builtin_amdgcn_mfma_f32_16x16x32_bf16(kf0, qvf, madd[kh][ks], 0,0,0);
        st[ks] = __builtin_amdgcn_mfma_f32_16x16x32_bf16(kf1, qtn, tbc, 0,0,0);
      }
      __builtin_amdgcn_s_setprio(0);
      #pragma unroll
      for (int ks=0; ks<4; ks++){
        float p0 = EXP2F(sv[ks][0]) * RCPF(1.f + EXP2F(st[ks][0]));
        float p1 = EXP2F(sv[ks][1]) * RCPF(1.f + EXP2F(st[ks][1]));
        float p2 = EXP2F(sv[ks][2]) * RCPF(1.f + EXP2F(st[ks][2]));
        float p3 = EXP2F(sv[ks][3]) * RCPF(1.f + EXP2F(st[ks][3]));
        union { unsigned u[2]; unsigned long long ll; } W;
        W.u[0] = pk2bf(p0,p1); W.u[1] = pk2bf(p2,p3);
        *(unsigned long long*)(Pw + ((ks*16 + g*4) ^ swp)) = W.ll;
      }
      #pragma unroll
      for (int ks2=0; ks2<2; ks2++){
        bf16x8 pf = *(const bf16x8*)(Pw + ((ks2*32 + g*8) ^ swp));
        __builtin_amdgcn_s_setprio(1);
        lsum = __builtin_amdgcn_mfma_f32_16x16x32_bf16(onesf, pf, lsum, 0,0,0);
        #pragma unroll
        for (int db=0; db<4; db++){
          int vrow = db*16 + lr;
          bf16x8 vf = *(const bf16x8*)(&Vc[vrow*128] + ((kh*64 + ks2*32 + g*8) ^ ((vrow&15)*8)));
          oT[db] = __builtin_amdgcn_mfma_f32_16x16x32_bf16(vf, pf, oT[db], 0,0,0);
        }
        __builtin_amdgcn_s_setprio(0);
      }
    }
    __syncthreads();
    unsigned short* tp;
    tp = Kc; Kc = Kn; Kn = tp;
    tp = Vc; Vc = Vn; Vn = tp;
  }

  float linv = (lsum[0] > 0.f) ? RCPF(lsum[0]) : 0.f;
  int srow = q0 + wv*16 + lr;
  unsigned short* Ob = Obuf + ((size_t)b*Sq + srow)*HIDq + h*HDq;
  #pragma unroll
  for (int db=0; db<4; db++){
    union { unsigned u[2]; unsigned long long ll; } W;
    W.u[0] = pk2bf(oT[db][0]*linv, oT[db][1]*linv);
    W.u[1] = pk2bf(oT[db][2]*linv, oT[db][3]*linv);
    *(unsigned long long*)(Ob + db*16 + g*4) = W.ll;
  }
}

extern "C" void kernel_launch(void* const* d_in, const int* in_sizes, int n_in,
                              void* d_out, int out_size, void* d_ws, size_t ws_size,
                              hipStream_t stream) {
  const float* x     = (const float*)d_in[0];
  const float* q_w   = (const float*)d_in[1];
  const float* q_b   = (const float*)d_in[2];
  const float* k_w   = (const float*)d_in[3];
  const float* k_b   = (const float*)d_in[4];
  const float* v_w   = (const float*)d_in[5];
  const float* v_b   = (const float*)d_in[6];
  const float* out_w = (const float*)d_in[7];
  const float* out_b = (const float*)d_in[8];
  const float* Tb    = (const float*)d_in[9];
  const float* tbias = (const float*)d_in[10];
  const int*   mask  = (const int*)d_in[11];

  const size_t MROWS = 4096;             // B*S
  unsigned short* xbf  = (unsigned short*)d_ws;           // 4M shorts
  unsigned short* wT   = xbf  + MROWS*HIDq;               // 4 x 1M
  unsigned short* Qeff = wT   + (size_t)4*HIDq*HIDq;      // (B,NH,S,HD), prescaled
  unsigned short* Keff = Qeff + MROWS*HIDq;
  unsigned short* Vt   = Keff + MROWS*HIDq;               // (B,NH,HD,S) transposed
  unsigned short* Obuf = Vt   + MROWS*HIDq;               // (B,S,HID) bf16
  float*          Mf   = (float*)(Obuf + MROWS*HIDq);     // (B,S) f32 mask adds

  int n8 = (int)(MROWS*HIDq/8);
  convert_x<<<dim3(n8/256 + 2), dim3(256), 0, stream>>>(x, xbf, n8, mask, Mf);
  transpose_w<<<dim3(32,32,4), dim3(32,8), 0, stream>>>(q_w, k_w, v_w, out_w, wT);

  gemm_qkv<<<dim3(24,32), dim3(256), 0, stream>>>(xbf, wT, q_b, k_b, v_b, Qeff, Keff, Vt);

  attn_kernel<<<dim3(512), dim3(512), 0, stream>>>(Qeff, Keff, Vt, Tb, tbias, Mf, Obuf);

  gemm_out<<<dim3(8,32), dim3(256), 0, stream>>>(Obuf, wT + (size_t)3*HIDq*HIDq, out_b, (float*)d_out);
}